// Round 3
// baseline (852.696 us; speedup 1.0000x reference)
//
#include <hip/hip_runtime.h>
#include <hip/hip_bf16.h>
#include <math.h>

#define BATCH 2
#define LSEQ 16384
#define DM 60
#define DI 120
#define DSTATE 16
#define NCH 256
#define TCH 64    // LSEQ / NCH
#define HH 128
#define WWIDTH 128

__device__ __forceinline__ float sigmoidf_(float x){ return 1.0f/(1.0f + __expf(-x)); }
__device__ __forceinline__ float siluf_(float x){ return x * sigmoidf_(x); }
__device__ __forceinline__ float softplusf_(float x){ return (x > 20.0f) ? x : log1pf(__expf(x)); }

__device__ __forceinline__ float waveReduceSum(float v){
  #pragma unroll
  for (int off = 32; off > 0; off >>= 1) v += __shfl_xor(v, off, 64);
  return v;
}

// ---------------- LN + in_proj (60 -> 240), split xin / silu(z) ----------------
__global__ __launch_bounds__(256) void k_ln_inproj(
    const float* __restrict__ src,
    const float* __restrict__ ln_w, const float* __restrict__ ln_b,
    const float* __restrict__ ipw,          // 240x60 row-major (layer base)
    float* __restrict__ xin, float* __restrict__ zs)
{
  __shared__ float Wl[240*61];   // stride 61 -> conflict-free
  __shared__ float hn[4][DM];
  const int tid = threadIdx.x;
  for (int i = tid; i < 240*DM; i += 256){
    int o = i/DM, k = i%DM;
    Wl[o*61+k] = ipw[i];
  }
  __syncthreads();
  const int r = tid >> 6, lane = tid & 63;
  const int row = blockIdx.x*4 + r;
  float v = 0.f;
  if (lane < DM) v = src[(size_t)row*DM+lane];
  float mu = waveReduceSum(v) * (1.0f/DM);
  float dv = (lane < DM) ? (v - mu) : 0.f;
  float var = waveReduceSum(dv*dv) * (1.0f/DM);
  float rs = rsqrtf(var + 1e-5f);
  if (lane < DM)
    hn[r][lane] = dv*rs*ln_w[lane] + ln_b[lane];
  __syncthreads();
  #pragma unroll
  for (int j = 0; j < 4; j++){
    int o = lane + j*64;
    if (o < 240){
      float acc = 0.f;
      const float* wrow = &Wl[o*61];
      #pragma unroll
      for (int k = 0; k < DM; k++) acc += wrow[k]*hn[r][k];
      if (o < DI) xin[(size_t)row*DI + o] = acc;
      else        zs[(size_t)row*DI + (o-DI)] = siluf_(acc);
    }
  }
}

// ---------------- depthwise causal conv1d (4 taps) + silu ----------------
__global__ __launch_bounds__(256) void k_conv1d(
    const float* __restrict__ xin, const float* __restrict__ cw, const float* __restrict__ cb,
    float* __restrict__ xc)
{
  int g = blockIdx.x*256 + threadIdx.x;
  if (g >= BATCH*LSEQ*DI) return;
  int d = g % DI;
  int l = (g / DI) % LSEQ;
  int b = g / (DI*LSEQ);
  float acc = cb[d];
  #pragma unroll
  for (int k = 0; k < 4; k++){
    int ll = l - 3 + k;
    if (ll >= 0) acc += cw[d*4+k] * xin[((size_t)b*LSEQ+ll)*DI + d];
  }
  xc[g] = siluf_(acc);
}

// ---------------- x_proj (120->36) + dt_proj (4->120) + softplus ----------------
__global__ __launch_bounds__(256) void k_xproj(
    const float* __restrict__ xc, const float* __restrict__ xpw,
    const float* __restrict__ dtw, const float* __restrict__ dtb,
    float* __restrict__ delta, float* __restrict__ BC)
{
  __shared__ float Wx[36*121];
  __shared__ float Wd[DI*5];
  __shared__ float bd[DI];
  __shared__ float xr[4][DI];
  __shared__ float dtsh[4][4];
  const int tid = threadIdx.x;
  for (int i = tid; i < 36*DI; i += 256){ int o=i/DI,k=i%DI; Wx[o*121+k] = xpw[i]; }
  for (int i = tid; i < DI*4; i += 256){ int o=i/4,k=i%4; Wd[o*5+k] = dtw[i]; }
  for (int i = tid; i < DI; i += 256) bd[i] = dtb[i];
  __syncthreads();
  const int r = tid>>6, lane = tid&63;
  const int row = blockIdx.x*4 + r;
  xr[r][lane] = xc[(size_t)row*DI + lane];
  if (lane + 64 < DI) xr[r][lane+64] = xc[(size_t)row*DI + lane + 64];
  __syncthreads();
  if (lane < 36){
    float acc = 0.f;
    const float* wrow = &Wx[lane*121];
    #pragma unroll
    for (int k = 0; k < DI; k++) acc += wrow[k]*xr[r][k];
    if (lane < 4) dtsh[r][lane] = acc;
    else          BC[(size_t)row*32 + (lane-4)] = acc;  // lanes 4..35 -> B(16),C(16)
  }
  __syncthreads();
  #pragma unroll
  for (int j = 0; j < 2; j++){
    int o = lane + j*64;
    if (o < DI){
      float acc = bd[o];
      #pragma unroll
      for (int rr = 0; rr < 4; rr++) acc += dtsh[r][rr]*Wd[o*5+rr];
      delta[(size_t)row*DI + o] = softplusf_(acc);
    }
  }
}

// ---------------- scan pass 1: per-chunk (prod dA, h_end with h0=0) ----------------
__global__ __launch_bounds__(128) void k_scan1(
    const float* __restrict__ delta, const float* __restrict__ xc,
    const float* __restrict__ BC, const float* __restrict__ A_log,
    float* __restrict__ ap, float* __restrict__ he)
{
  __shared__ float Bl[TCH*16];
  const int tid = threadIdx.x;
  const int c = blockIdx.x % NCH, b = blockIdx.x / NCH;
  const size_t rowbase = (size_t)b*LSEQ + (size_t)c*TCH;
  for (int i = tid; i < TCH*16; i += 128){
    int t = i >> 4, n = i & 15;
    Bl[i] = BC[(rowbase + t)*32 + n];
  }
  __syncthreads();
  const int d = tid;
  if (d >= DI) return;
  float A2[16], h[16], apv[16];
  #pragma unroll
  for (int n = 0; n < 16; n++){
    A2[n] = -__expf(A_log[d*16+n]) * 1.44269504f;
    h[n] = 0.f; apv[n] = 1.f;
  }
  for (int t = 0; t < TCH; t++){
    float del = delta[(rowbase+t)*DI + d];
    float xcv = xc[(rowbase+t)*DI + d];
    float dx = del * xcv;
    #pragma unroll
    for (int n = 0; n < 16; n++){
      float dA = exp2f(del * A2[n]);
      apv[n] *= dA;
      h[n] = dA*h[n] + dx*Bl[t*16+n];
    }
  }
  int base = (c*BATCH + b)*(DI*16) + d*16;   // layout [c][b][d][n]
  #pragma unroll
  for (int n = 0; n < 16; n++){ ap[base+n] = apv[n]; he[base+n] = h[n]; }
}

// ---------------- scan pass 2: scan over chunks, write h0 in place over ap ----------------
__global__ __launch_bounds__(256) void k_scan2(float* __restrict__ ap, const float* __restrict__ he)
{
  int g = blockIdx.x*256 + threadIdx.x;
  if (g >= BATCH*DI*16) return;
  float H = 0.f;
  const int stride = BATCH*DI*16;  // 3840
  int idx = g;
  #pragma unroll 4
  for (int c = 0; c < NCH; c++){
    float a = ap[idx];
    float hend = he[idx];
    ap[idx] = H;           // store chunk-initial state
    H = a*H + hend;
    idx += stride;
  }
}

// ---------------- scan pass 3: replay chunk from true h0, fuse +D*xc and *silu(z) ----------------
__global__ __launch_bounds__(128) void k_scan3(
    const float* __restrict__ delta, const float* __restrict__ xc,
    const float* __restrict__ BC, const float* __restrict__ zs,
    const float* __restrict__ h0, const float* __restrict__ A_log,
    const float* __restrict__ Dsk, float* __restrict__ y)
{
  __shared__ float BCl[TCH*32];
  const int tid = threadIdx.x;
  const int c = blockIdx.x % NCH, b = blockIdx.x / NCH;
  const size_t rowbase = (size_t)b*LSEQ + (size_t)c*TCH;
  for (int i = tid; i < TCH*32; i += 128)
    BCl[i] = BC[rowbase*32 + i];
  __syncthreads();
  const int d = tid;
  if (d >= DI) return;
  float A2[16], h[16];
  int base = (c*BATCH + b)*(DI*16) + d*16;
  #pragma unroll
  for (int n = 0; n < 16; n++){
    A2[n] = -__expf(A_log[d*16+n]) * 1.44269504f;
    h[n] = h0[base+n];
  }
  float Dv = Dsk[d];
  for (int t = 0; t < TCH; t++){
    float del = delta[(rowbase+t)*DI + d];
    float xcv = xc[(rowbase+t)*DI + d];
    float zv  = zs[(rowbase+t)*DI + d];
    float dx = del * xcv;
    float acc = 0.f;
    #pragma unroll
    for (int n = 0; n < 16; n++){
      float dA = exp2f(del * A2[n]);
      h[n] = dA*h[n] + dx*BCl[t*32+n];
      acc += h[n]*BCl[t*32+16+n];
    }
    y[(rowbase+t)*DI + d] = (acc + Dv*xcv) * zv;
  }
}

// ---------------- out_proj (120 -> 60) ----------------
__global__ __launch_bounds__(256) void k_outproj(
    const float* __restrict__ y, const float* __restrict__ opw,
    float* __restrict__ hout)
{
  __shared__ float Wl[DM*121];
  __shared__ float yr[4][DI];
  const int tid = threadIdx.x;
  for (int i = tid; i < DM*DI; i += 256){ int o=i/DI,k=i%DI; Wl[o*121+k]=opw[i]; }
  __syncthreads();
  const int r = tid>>6, lane = tid&63;
  const int row = blockIdx.x*4 + r;
  yr[r][lane] = y[(size_t)row*DI+lane];
  if (lane+64 < DI) yr[r][lane+64] = y[(size_t)row*DI+lane+64];
  __syncthreads();
  if (lane < DM){
    float acc = 0.f;
    const float* wrow = &Wl[lane*121];
    #pragma unroll
    for (int k = 0; k < DI; k++) acc += wrow[k]*yr[r][k];
    hout[(size_t)row*DM + lane] = acc;
  }
}

// ---------------- conv2d weight transpose: w[co][ci][ky][kx] -> wT[ci*9+r][co] ----------------
__global__ __launch_bounds__(256) void k_wT(const float* __restrict__ w, float* __restrict__ wT)
{
  int g = blockIdx.x*256 + threadIdx.x;
  if (g >= 540*DM) return;
  int co = g % DM;
  int idx = g / DM;
  int ci = idx / 9, r = idx % 9;
  wT[g] = w[(co*DM + ci)*9 + r];
}

// ---------------- 3x3 SAME conv2d + bias + residual, write fp32 ----------------
__global__ __launch_bounds__(256) void k_conv2d(
    const float* __restrict__ hin, const float* __restrict__ wT,
    const float* __restrict__ cb, const float* __restrict__ xres,
    float* __restrict__ out)
{
  __shared__ float tile[3*66*DM];  // rows y-1..y+1, x0-1..x0+64, 60 ch
  const int tid = threadIdx.x;
  int blk = blockIdx.x;
  int xhalf = blk & 1;
  int yy = (blk >> 1) & 127;
  int b = blk >> 8;
  int x0 = xhalf*64;
  for (int i = tid; i < 3*66*DM; i += 256){
    int ci = i % DM;
    int xx = (i / DM) % 66;
    int row = i / (DM*66);
    int gy = yy - 1 + row, gx = x0 - 1 + xx;
    float v = 0.f;
    if (gy >= 0 && gy < HH && gx >= 0 && gx < WWIDTH)
      v = hin[((size_t)b*LSEQ + gy*WWIDTH + gx)*DM + ci];
    tile[i] = v;
  }
  __syncthreads();
  const int w = tid >> 6, lane = tid & 63;
  if (lane >= DM) return;
  float acc[16];
  #pragma unroll
  for (int p = 0; p < 16; p++) acc[p] = 0.f;
  for (int idx = 0; idx < 540; idx++){
    int rr = idx % 9;
    int ky = rr / 3, kx = rr % 3;
    float wv = wT[idx*DM + lane];
    const float* trow = &tile[(ky*66 + w*16 + kx)*DM + (idx/9)];
    #pragma unroll
    for (int p = 0; p < 16; p++)
      acc[p] += wv * trow[p*DM];
  }
  float bias = cb[lane];
  #pragma unroll
  for (int p = 0; p < 16; p++){
    int gx = x0 + w*16 + p;
    size_t o = ((size_t)b*LSEQ + yy*WWIDTH + gx)*DM + lane;
    out[o] = acc[p] + bias + xres[o];
  }
}

extern "C" void kernel_launch(void* const* d_in, const int* in_sizes, int n_in,
                              void* d_out, int out_size, void* d_ws, size_t ws_size,
                              hipStream_t stream)
{
  const float* x      = (const float*)d_in[0];
  const float* ln_w   = (const float*)d_in[1];
  const float* ln_b   = (const float*)d_in[2];
  const float* ipw    = (const float*)d_in[3];
  const float* cw     = (const float*)d_in[4];
  const float* cb1    = (const float*)d_in[5];
  const float* xpw    = (const float*)d_in[6];
  const float* dtw    = (const float*)d_in[7];
  const float* dtb    = (const float*)d_in[8];
  const float* A_log  = (const float*)d_in[9];
  const float* Dsk    = (const float*)d_in[10];
  const float* opw    = (const float*)d_in[11];
  const float* c2w    = (const float*)d_in[12];
  const float* c2b    = (const float*)d_in[13];
  float* out = (float*)d_out;

  float* ws = (float*)d_ws;
  size_t off = 0;
  float* xin   = ws + off; off += (size_t)BATCH*LSEQ*DI;
  float* zsb   = ws + off; off += (size_t)BATCH*LSEQ*DI;
  float* xcb   = ws + off; off += (size_t)BATCH*LSEQ*DI;
  float* dlt   = ws + off; off += (size_t)BATCH*LSEQ*DI;
  float* BC    = ws + off; off += (size_t)BATCH*LSEQ*32;
  float* apb   = ws + off; off += (size_t)NCH*BATCH*DI*16;
  float* heb   = ws + off; off += (size_t)NCH*BATCH*DI*16;
  float* hcur  = ws + off; off += (size_t)BATCH*LSEQ*DM;
  float* wTb   = ws + off; off += (size_t)540*DM;
  float* ybuf  = xin;   // xin dead after conv1d -> reuse for y

  const int rows = BATCH*LSEQ;
  for (int layer = 0; layer < 2; layer++){
    const float* src = (layer == 0) ? x : hcur;
    k_ln_inproj<<<rows/4, 256, 0, stream>>>(src, ln_w + layer*DM, ln_b + layer*DM,
                                            ipw + (size_t)layer*240*DM, xin, zsb);
    k_conv1d<<<(rows*DI+255)/256, 256, 0, stream>>>(xin, cw + layer*DI*4, cb1 + layer*DI, xcb);
    k_xproj<<<rows/4, 256, 0, stream>>>(xcb, xpw + (size_t)layer*36*DI, dtw + (size_t)layer*DI*4,
                                        dtb + layer*DI, dlt, BC);
    k_scan1<<<BATCH*NCH, 128, 0, stream>>>(dlt, xcb, BC, A_log + (size_t)layer*DI*16, apb, heb);
    k_scan2<<<(BATCH*DI*16+255)/256, 256, 0, stream>>>(apb, heb);
    k_scan3<<<BATCH*NCH, 128, 0, stream>>>(dlt, xcb, BC, zsb, apb, A_log + (size_t)layer*DI*16,
                                           Dsk + layer*DI, ybuf);
    k_outproj<<<rows/4, 256, 0, stream>>>(ybuf, opw + (size_t)layer*DM*DI, hcur);
  }
  k_wT<<<(540*DM+255)/256, 256, 0, stream>>>(c2w, wTb);
  k_conv2d<<<BATCH*HH*2, 256, 0, stream>>>(hcur, wTb, c2b, x, out);
}

// Round 4
// 674.876 us; speedup vs baseline: 1.2635x; 1.2635x over previous
//
#include <hip/hip_runtime.h>
#include <math.h>

#define BATCH 2
#define LSEQ 16384
#define DM 60
#define DI 120
#define NCH 256
#define TCH 64    // LSEQ / NCH
#define HH 128
#define WW 128

__device__ __forceinline__ float sigmoidf_(float x){ return 1.0f/(1.0f + __expf(-x)); }
__device__ __forceinline__ float siluf_(float x){ return x * sigmoidf_(x); }
__device__ __forceinline__ float softplusf_(float x){ return (x > 20.0f) ? x : log1pf(__expf(x)); }

__device__ __forceinline__ float waveReduceSum(float v){
  #pragma unroll
  for (int off = 32; off > 0; off >>= 1) v += __shfl_xor(v, off, 64);
  return v;
}

// =============== LN + in_proj (60 -> 240) as 64-row tiled GEMM ===============
// block = 64 rows, 256 threads. W^T staged once: [k][o] stride 244.
__global__ __launch_bounds__(256) void k_ln_inproj(
    const float* __restrict__ src,
    const float* __restrict__ ln_w, const float* __restrict__ ln_b,
    const float* __restrict__ ipw,          // [240][60] row-major
    float* __restrict__ xin, float* __restrict__ zs)
{
  __shared__ float WtB[60*244];   // 58.6 KB, [k][o]
  __shared__ float hnL[64*64];    // 16.4 KB, [r][k] stride 64 (b128-aligned)
  const int tid = threadIdx.x;
  for (int i = tid; i < 240*60; i += 256){
    int o = i/60, k = i%60;
    WtB[k*244 + o] = ipw[i];      // coalesced global read
  }
  const int wave = tid >> 6, lane = tid & 63;
  const int row0 = blockIdx.x*64;
  float lw = (lane < 60) ? ln_w[lane] : 0.f;
  float lb = (lane < 60) ? ln_b[lane] : 0.f;
  for (int rr = 0; rr < 16; rr++){
    int row = row0 + wave*16 + rr;
    float v = (lane < 60) ? src[(size_t)row*60 + lane] : 0.f;
    float mu = waveReduceSum(v) * (1.0f/60.0f);
    float dv = (lane < 60) ? (v - mu) : 0.f;
    float var = waveReduceSum(dv*dv) * (1.0f/60.0f);
    float rs = rsqrtf(var + 1e-5f);
    if (lane < 60) hnL[(wave*16+rr)*64 + lane] = dv*rs*lw + lb;
  }
  __syncthreads();
  if (tid < 240){
    const int cg = tid % 60, rg = tid / 60;   // 4 cols, 16 rows per thread
    float acc[16][4];
    #pragma unroll
    for (int r = 0; r < 16; r++){ acc[r][0]=0.f; acc[r][1]=0.f; acc[r][2]=0.f; acc[r][3]=0.f; }
    for (int kg = 0; kg < 15; kg++){
      int k = kg*4;
      float4 b0 = *(const float4*)&WtB[(k+0)*244 + cg*4];
      float4 b1 = *(const float4*)&WtB[(k+1)*244 + cg*4];
      float4 b2 = *(const float4*)&WtB[(k+2)*244 + cg*4];
      float4 b3 = *(const float4*)&WtB[(k+3)*244 + cg*4];
      #pragma unroll
      for (int r = 0; r < 16; r++){
        float4 a = *(const float4*)&hnL[(rg*16+r)*64 + k];
        acc[r][0] += a.x*b0.x + a.y*b1.x + a.z*b2.x + a.w*b3.x;
        acc[r][1] += a.x*b0.y + a.y*b1.y + a.z*b2.y + a.w*b3.y;
        acc[r][2] += a.x*b0.z + a.y*b1.z + a.z*b2.z + a.w*b3.z;
        acc[r][3] += a.x*b0.w + a.y*b1.w + a.z*b2.w + a.w*b3.w;
      }
    }
    const int c0 = cg*4;
    #pragma unroll
    for (int r = 0; r < 16; r++){
      int row = row0 + rg*16 + r;
      float4 v; v.x=acc[r][0]; v.y=acc[r][1]; v.z=acc[r][2]; v.w=acc[r][3];
      if (c0 < 120){
        *(float4*)&xin[(size_t)row*120 + c0] = v;
      } else {
        v.x = siluf_(v.x); v.y = siluf_(v.y); v.z = siluf_(v.z); v.w = siluf_(v.w);
        *(float4*)&zs[(size_t)row*120 + (c0-120)] = v;
      }
    }
  }
}

// =============== depthwise causal conv1d (4 taps) + silu (unchanged) ===============
__global__ __launch_bounds__(256) void k_conv1d(
    const float* __restrict__ xin, const float* __restrict__ cw, const float* __restrict__ cb,
    float* __restrict__ xc)
{
  int g = blockIdx.x*256 + threadIdx.x;
  if (g >= BATCH*LSEQ*DI) return;
  int d = g % DI;
  int l = (g / DI) % LSEQ;
  int b = g / (DI*LSEQ);
  float acc = cb[d];
  #pragma unroll
  for (int k = 0; k < 4; k++){
    int ll = l - 3 + k;
    if (ll >= 0) acc += cw[d*4+k] * xin[((size_t)b*LSEQ+ll)*DI + d];
  }
  xc[g] = siluf_(acc);
}

// =============== x_proj (120->36) + dt_proj + softplus, 64-row tiled ===============
__global__ __launch_bounds__(256) void k_xproj(
    const float* __restrict__ xc, const float* __restrict__ xpw,
    const float* __restrict__ dtw, const float* __restrict__ dtb,
    float* __restrict__ delta, float* __restrict__ BC)
{
  __shared__ float AL[64*124];    // 31.7 KB, [r][k] stride 124 (496B, 16B-mult)
  __shared__ float WxT[120*36];   // 17.3 KB, [k][o]
  __shared__ float Wd5[120*5];
  __shared__ float bdL[120];
  __shared__ float dtsh[64*4];
  const int tid = threadIdx.x;
  const int row0 = blockIdx.x*64;
  for (int i = tid; i < 36*120; i += 256){ int o=i/120, k=i%120; WxT[k*36+o] = xpw[i]; }
  for (int i = tid; i < 480; i += 256){ int d=i/4, r=i%4; Wd5[d*5+r] = dtw[i]; }
  for (int i = tid; i < 120; i += 256) bdL[i] = dtb[i];
  for (int i = tid; i < 64*120; i += 256){
    int r = i/120, c = i%120;
    AL[r*124 + c] = xc[((size_t)row0 + r)*120 + c];
  }
  __syncthreads();
  if (tid < 144){
    const int cg = tid % 9, rg = tid / 9;   // 4 cols, 4 rows
    float acc[4][4];
    #pragma unroll
    for (int r = 0; r < 4; r++){ acc[r][0]=0.f; acc[r][1]=0.f; acc[r][2]=0.f; acc[r][3]=0.f; }
    for (int kg = 0; kg < 30; kg++){
      int k = kg*4;
      float4 b0 = *(const float4*)&WxT[(k+0)*36 + cg*4];
      float4 b1 = *(const float4*)&WxT[(k+1)*36 + cg*4];
      float4 b2 = *(const float4*)&WxT[(k+2)*36 + cg*4];
      float4 b3 = *(const float4*)&WxT[(k+3)*36 + cg*4];
      #pragma unroll
      for (int r = 0; r < 4; r++){
        float4 a = *(const float4*)&AL[(rg*4+r)*124 + k];
        acc[r][0] += a.x*b0.x + a.y*b1.x + a.z*b2.x + a.w*b3.x;
        acc[r][1] += a.x*b0.y + a.y*b1.y + a.z*b2.y + a.w*b3.y;
        acc[r][2] += a.x*b0.z + a.y*b1.z + a.z*b2.z + a.w*b3.z;
        acc[r][3] += a.x*b0.w + a.y*b1.w + a.z*b2.w + a.w*b3.w;
      }
    }
    #pragma unroll
    for (int r = 0; r < 4; r++){
      int row = rg*4 + r;
      float4 v; v.x=acc[r][0]; v.y=acc[r][1]; v.z=acc[r][2]; v.w=acc[r][3];
      if (cg == 0) *(float4*)&dtsh[row*4] = v;
      else         *(float4*)&BC[((size_t)row0 + row)*32 + (cg*4 - 4)] = v;
    }
  }
  __syncthreads();
  for (int i = tid; i < 64*120; i += 256){
    int row = i/120, d = i%120;
    float4 t = *(const float4*)&dtsh[row*4];
    float acc = bdL[d] + t.x*Wd5[d*5] + t.y*Wd5[d*5+1] + t.z*Wd5[d*5+2] + t.w*Wd5[d*5+3];
    delta[((size_t)row0 + row)*120 + d] = softplusf_(acc);
  }
}

// =============== scan pass 1 (unchanged) ===============
__global__ __launch_bounds__(128) void k_scan1(
    const float* __restrict__ delta, const float* __restrict__ xc,
    const float* __restrict__ BC, const float* __restrict__ A_log,
    float* __restrict__ ap, float* __restrict__ he)
{
  __shared__ float Bl[TCH*16];
  const int tid = threadIdx.x;
  const int c = blockIdx.x % NCH, b = blockIdx.x / NCH;
  const size_t rowbase = (size_t)b*LSEQ + (size_t)c*TCH;
  for (int i = tid; i < TCH*16; i += 128){
    int t = i >> 4, n = i & 15;
    Bl[i] = BC[(rowbase + t)*32 + n];
  }
  __syncthreads();
  const int d = tid;
  if (d >= DI) return;
  float A2[16], h[16], apv[16];
  #pragma unroll
  for (int n = 0; n < 16; n++){
    A2[n] = -__expf(A_log[d*16+n]) * 1.44269504f;
    h[n] = 0.f; apv[n] = 1.f;
  }
  for (int t = 0; t < TCH; t++){
    float del = delta[(rowbase+t)*DI + d];
    float xcv = xc[(rowbase+t)*DI + d];
    float dx = del * xcv;
    #pragma unroll
    for (int n = 0; n < 16; n++){
      float dA = exp2f(del * A2[n]);
      apv[n] *= dA;
      h[n] = dA*h[n] + dx*Bl[t*16+n];
    }
  }
  int base = (c*BATCH + b)*(DI*16) + d*16;
  #pragma unroll
  for (int n = 0; n < 16; n++){ ap[base+n] = apv[n]; he[base+n] = h[n]; }
}

// =============== scan pass 2 (unchanged) ===============
__global__ __launch_bounds__(256) void k_scan2(float* __restrict__ ap, const float* __restrict__ he)
{
  int g = blockIdx.x*256 + threadIdx.x;
  if (g >= BATCH*DI*16) return;
  float H = 0.f;
  const int stride = BATCH*DI*16;
  int idx = g;
  #pragma unroll 4
  for (int c = 0; c < NCH; c++){
    float a = ap[idx];
    float hend = he[idx];
    ap[idx] = H;
    H = a*H + hend;
    idx += stride;
  }
}

// =============== scan pass 3 (unchanged) ===============
__global__ __launch_bounds__(128) void k_scan3(
    const float* __restrict__ delta, const float* __restrict__ xc,
    const float* __restrict__ BC, const float* __restrict__ zs,
    const float* __restrict__ h0, const float* __restrict__ A_log,
    const float* __restrict__ Dsk, float* __restrict__ y)
{
  __shared__ float BCl[TCH*32];
  const int tid = threadIdx.x;
  const int c = blockIdx.x % NCH, b = blockIdx.x / NCH;
  const size_t rowbase = (size_t)b*LSEQ + (size_t)c*TCH;
  for (int i = tid; i < TCH*32; i += 128)
    BCl[i] = BC[rowbase*32 + i];
  __syncthreads();
  const int d = tid;
  if (d >= DI) return;
  float A2[16], h[16];
  int base = (c*BATCH + b)*(DI*16) + d*16;
  #pragma unroll
  for (int n = 0; n < 16; n++){
    A2[n] = -__expf(A_log[d*16+n]) * 1.44269504f;
    h[n] = h0[base+n];
  }
  float Dv = Dsk[d];
  for (int t = 0; t < TCH; t++){
    float del = delta[(rowbase+t)*DI + d];
    float xcv = xc[(rowbase+t)*DI + d];
    float zv  = zs[(rowbase+t)*DI + d];
    float dx = del * xcv;
    float acc = 0.f;
    #pragma unroll
    for (int n = 0; n < 16; n++){
      float dA = exp2f(del * A2[n]);
      h[n] = dA*h[n] + dx*BCl[t*32+n];
      acc += h[n]*BCl[t*32+16+n];
    }
    y[(rowbase+t)*DI + d] = (acc + Dv*xcv) * zv;
  }
}

// =============== out_proj (120 -> 60), 64-row tiled ===============
__global__ __launch_bounds__(256) void k_outproj(
    const float* __restrict__ y, const float* __restrict__ opw,
    float* __restrict__ hout)
{
  __shared__ float YL[64*124];   // 31.7 KB
  __shared__ float OT[120*60];   // 28.8 KB, [k][o]
  const int tid = threadIdx.x;
  const int row0 = blockIdx.x*64;
  for (int i = tid; i < 60*120; i += 256){ int o=i/120, k=i%120; OT[k*60+o] = opw[i]; }
  for (int i = tid; i < 64*120; i += 256){
    int r = i/120, c = i%120;
    YL[r*124 + c] = y[((size_t)row0 + r)*120 + c];
  }
  __syncthreads();
  if (tid < 240){
    const int cg = tid % 15, rg = tid / 15;   // 4 cols, 4 rows
    float acc[4][4];
    #pragma unroll
    for (int r = 0; r < 4; r++){ acc[r][0]=0.f; acc[r][1]=0.f; acc[r][2]=0.f; acc[r][3]=0.f; }
    for (int kg = 0; kg < 30; kg++){
      int k = kg*4;
      float4 b0 = *(const float4*)&OT[(k+0)*60 + cg*4];
      float4 b1 = *(const float4*)&OT[(k+1)*60 + cg*4];
      float4 b2 = *(const float4*)&OT[(k+2)*60 + cg*4];
      float4 b3 = *(const float4*)&OT[(k+3)*60 + cg*4];
      #pragma unroll
      for (int r = 0; r < 4; r++){
        float4 a = *(const float4*)&YL[(rg*4+r)*124 + k];
        acc[r][0] += a.x*b0.x + a.y*b1.x + a.z*b2.x + a.w*b3.x;
        acc[r][1] += a.x*b0.y + a.y*b1.y + a.z*b2.y + a.w*b3.y;
        acc[r][2] += a.x*b0.z + a.y*b1.z + a.z*b2.z + a.w*b3.z;
        acc[r][3] += a.x*b0.w + a.y*b1.w + a.z*b2.w + a.w*b3.w;
      }
    }
    #pragma unroll
    for (int r = 0; r < 4; r++){
      int row = row0 + rg*4 + r;
      float4 v; v.x=acc[r][0]; v.y=acc[r][1]; v.z=acc[r][2]; v.w=acc[r][3];
      *(float4*)&hout[(size_t)row*60 + cg*4] = v;
    }
  }
}

// =============== conv2d weights: w[co][ci][3][3] -> wT64[idx][g*16+j], co=g*15+j ===============
__global__ __launch_bounds__(256) void k_wT(const float* __restrict__ w, float* __restrict__ wT64)
{
  int i = blockIdx.x*256 + threadIdx.x;
  if (i >= 540*64) return;
  int idx = i / 64, s = i % 64;
  int g = s / 16, j = s % 16;
  int ci = idx / 9, r = idx % 9;
  float v = 0.f;
  if (j < 15){
    int co = g*15 + j;
    v = w[((size_t)co*60 + ci)*9 + r];
  }
  wT64[i] = v;
}

// =============== 3x3 SAME conv2d + bias + residual ===============
// block: 64-px strip; wave -> 15 couts, lane -> px. Weights LDS-chunked.
__global__ __launch_bounds__(256) void k_conv2d(
    const float* __restrict__ hin, const float* __restrict__ wT64,
    const float* __restrict__ cb, const float* __restrict__ xres,
    float* __restrict__ out)
{
  __shared__ float tile[3*66*61];   // 48.3 KB, [(row*66+xx)*61 + ci]
  __shared__ float wl[108*64];      // 27.6 KB (12-ci chunk)
  const int tid = threadIdx.x;
  const int blk = blockIdx.x;
  const int xhalf = blk & 1;
  const int yy = (blk >> 1) & 127;
  const int b = blk >> 8;
  const int x0 = xhalf*64;
  for (int i = tid; i < 3*66*60; i += 256){
    int row = i / (66*60);
    int rem = i % (66*60);
    int xx = rem / 60, ci = rem % 60;
    int gy = yy - 1 + row, gx = x0 - 1 + xx;
    float v = 0.f;
    if (gy >= 0 && gy < HH && gx >= 0 && gx < WW)
      v = hin[((size_t)b*LSEQ + gy*WW + gx)*60 + ci];
    tile[(row*66 + xx)*61 + ci] = v;
  }
  const int wave = tid >> 6, lane = tid & 63;
  float acc[15];
  #pragma unroll
  for (int j = 0; j < 15; j++) acc[j] = 0.f;
  for (int chunk = 0; chunk < 5; chunk++){
    const int ci0 = chunk*12;
    __syncthreads();
    for (int i = tid; i < 108*64; i += 256)
      wl[i] = wT64[(size_t)ci0*9*64 + i];
    __syncthreads();
    for (int il = 0; il < 108; il++){
      int ci = ci0 + il/9;
      int r = il % 9;
      int ky = r/3, kx = r%3;
      float xv = tile[(ky*66 + lane + kx)*61 + ci];
      float4 w0 = *(const float4*)&wl[il*64 + wave*16 + 0];
      float4 w1 = *(const float4*)&wl[il*64 + wave*16 + 4];
      float4 w2 = *(const float4*)&wl[il*64 + wave*16 + 8];
      float4 w3 = *(const float4*)&wl[il*64 + wave*16 + 12];
      acc[0]  += xv*w0.x; acc[1]  += xv*w0.y; acc[2]  += xv*w0.z; acc[3]  += xv*w0.w;
      acc[4]  += xv*w1.x; acc[5]  += xv*w1.y; acc[6]  += xv*w1.z; acc[7]  += xv*w1.w;
      acc[8]  += xv*w2.x; acc[9]  += xv*w2.y; acc[10] += xv*w2.z; acc[11] += xv*w2.w;
      acc[12] += xv*w3.x; acc[13] += xv*w3.y; acc[14] += xv*w3.z;
    }
  }
  const size_t pixbase = ((size_t)b*LSEQ + yy*WW + x0 + lane)*60;
  #pragma unroll
  for (int j = 0; j < 15; j++){
    int co = wave*15 + j;
    out[pixbase + co] = acc[j] + cb[co] + xres[pixbase + co];
  }
}

extern "C" void kernel_launch(void* const* d_in, const int* in_sizes, int n_in,
                              void* d_out, int out_size, void* d_ws, size_t ws_size,
                              hipStream_t stream)
{
  const float* x      = (const float*)d_in[0];
  const float* ln_w   = (const float*)d_in[1];
  const float* ln_b   = (const float*)d_in[2];
  const float* ipw    = (const float*)d_in[3];
  const float* cw     = (const float*)d_in[4];
  const float* cb1    = (const float*)d_in[5];
  const float* xpw    = (const float*)d_in[6];
  const float* dtw    = (const float*)d_in[7];
  const float* dtb    = (const float*)d_in[8];
  const float* A_log  = (const float*)d_in[9];
  const float* Dsk    = (const float*)d_in[10];
  const float* opw    = (const float*)d_in[11];
  const float* c2w    = (const float*)d_in[12];
  const float* c2b    = (const float*)d_in[13];
  float* out = (float*)d_out;

  float* ws = (float*)d_ws;
  size_t off = 0;
  float* xin   = ws + off; off += (size_t)BATCH*LSEQ*DI;
  float* zsb   = ws + off; off += (size_t)BATCH*LSEQ*DI;
  float* xcb   = ws + off; off += (size_t)BATCH*LSEQ*DI;
  float* dlt   = ws + off; off += (size_t)BATCH*LSEQ*DI;
  float* BC    = ws + off; off += (size_t)BATCH*LSEQ*32;
  float* apb   = ws + off; off += (size_t)NCH*BATCH*DI*16;
  float* heb   = ws + off; off += (size_t)NCH*BATCH*DI*16;
  float* hcur  = ws + off; off += (size_t)BATCH*LSEQ*DM;
  float* wTb   = ws + off; off += (size_t)540*64;
  float* ybuf  = xin;   // xin dead after conv1d -> reuse for y

  const int rows = BATCH*LSEQ;
  for (int layer = 0; layer < 2; layer++){
    const float* src = (layer == 0) ? x : hcur;
    k_ln_inproj<<<rows/64, 256, 0, stream>>>(src, ln_w + layer*DM, ln_b + layer*DM,
                                             ipw + (size_t)layer*240*DM, xin, zsb);
    k_conv1d<<<(rows*DI+255)/256, 256, 0, stream>>>(xin, cw + layer*DI*4, cb1 + layer*DI, xcb);
    k_xproj<<<rows/64, 256, 0, stream>>>(xcb, xpw + (size_t)layer*36*DI, dtw + (size_t)layer*DI*4,
                                         dtb + layer*DI, dlt, BC);
    k_scan1<<<BATCH*NCH, 128, 0, stream>>>(dlt, xcb, BC, A_log + (size_t)layer*DI*16, apb, heb);
    k_scan2<<<(BATCH*DI*16+255)/256, 256, 0, stream>>>(apb, heb);
    k_scan3<<<BATCH*NCH, 128, 0, stream>>>(dlt, xcb, BC, zsb, apb, A_log + (size_t)layer*DI*16,
                                           Dsk + layer*DI, ybuf);
    k_outproj<<<rows/64, 256, 0, stream>>>(ybuf, opw + (size_t)layer*DM*DI, hcur);
  }
  k_wT<<<(540*64+255)/256, 256, 0, stream>>>(c2w, wTb);
  k_conv2d<<<BATCH*HH*2, 256, 0, stream>>>(hcur, wTb, c2b, x, out);
}

// Round 5
// 600.748 us; speedup vs baseline: 1.4194x; 1.1234x over previous
//
#include <hip/hip_runtime.h>
#include <math.h>

#define BATCH 2
#define LSEQ 16384
#define DM 60
#define DI 120
#define NCH 512
#define TCH 32    // LSEQ / NCH
#define HH 128
#define WW 128

__device__ __forceinline__ float sigmoidf_(float x){ return 1.0f/(1.0f + __expf(-x)); }
__device__ __forceinline__ float siluf_(float x){ return x * sigmoidf_(x); }
__device__ __forceinline__ float softplusf_(float x){ return (x > 20.0f) ? x : log1pf(__expf(x)); }

__device__ __forceinline__ float waveReduceSum(float v){
  #pragma unroll
  for (int off = 32; off > 0; off >>= 1) v += __shfl_xor(v, off, 64);
  return v;
}

// powers: dA[n] = r^(n+1), log-depth tree
__device__ __forceinline__ void powers16(float r, float* dA){
  dA[0] = r;
  #pragma unroll
  for (int n = 1; n < 16; n++) dA[n] = dA[(n-1)>>1] * dA[n>>1];
}

// =============== LN + in_proj (60 -> 240) as 64-row tiled GEMM ===============
__global__ __launch_bounds__(256) void k_ln_inproj(
    const float* __restrict__ src,
    const float* __restrict__ ln_w, const float* __restrict__ ln_b,
    const float* __restrict__ ipw,
    float* __restrict__ xin, float* __restrict__ zs)
{
  __shared__ float WtB[60*244];
  __shared__ float hnL[64*64];
  const int tid = threadIdx.x;
  for (int i = tid; i < 240*60; i += 256){
    int o = i/60, k = i%60;
    WtB[k*244 + o] = ipw[i];
  }
  const int wave = tid >> 6, lane = tid & 63;
  const int row0 = blockIdx.x*64;
  float lw = (lane < 60) ? ln_w[lane] : 0.f;
  float lb = (lane < 60) ? ln_b[lane] : 0.f;
  for (int rr = 0; rr < 16; rr++){
    int row = row0 + wave*16 + rr;
    float v = (lane < 60) ? src[(size_t)row*60 + lane] : 0.f;
    float mu = waveReduceSum(v) * (1.0f/60.0f);
    float dv = (lane < 60) ? (v - mu) : 0.f;
    float var = waveReduceSum(dv*dv) * (1.0f/60.0f);
    float rs = rsqrtf(var + 1e-5f);
    if (lane < 60) hnL[(wave*16+rr)*64 + lane] = dv*rs*lw + lb;
  }
  __syncthreads();
  if (tid < 240){
    const int cg = tid % 60, rg = tid / 60;
    float acc[16][4];
    #pragma unroll
    for (int r = 0; r < 16; r++){ acc[r][0]=0.f; acc[r][1]=0.f; acc[r][2]=0.f; acc[r][3]=0.f; }
    for (int kg = 0; kg < 15; kg++){
      int k = kg*4;
      float4 b0 = *(const float4*)&WtB[(k+0)*244 + cg*4];
      float4 b1 = *(const float4*)&WtB[(k+1)*244 + cg*4];
      float4 b2 = *(const float4*)&WtB[(k+2)*244 + cg*4];
      float4 b3 = *(const float4*)&WtB[(k+3)*244 + cg*4];
      #pragma unroll
      for (int r = 0; r < 16; r++){
        float4 a = *(const float4*)&hnL[(rg*16+r)*64 + k];
        acc[r][0] += a.x*b0.x + a.y*b1.x + a.z*b2.x + a.w*b3.x;
        acc[r][1] += a.x*b0.y + a.y*b1.y + a.z*b2.y + a.w*b3.y;
        acc[r][2] += a.x*b0.z + a.y*b1.z + a.z*b2.z + a.w*b3.z;
        acc[r][3] += a.x*b0.w + a.y*b1.w + a.z*b2.w + a.w*b3.w;
      }
    }
    const int c0 = cg*4;
    #pragma unroll
    for (int r = 0; r < 16; r++){
      int row = row0 + rg*16 + r;
      float4 v; v.x=acc[r][0]; v.y=acc[r][1]; v.z=acc[r][2]; v.w=acc[r][3];
      if (c0 < 120){
        *(float4*)&xin[(size_t)row*120 + c0] = v;
      } else {
        v.x = siluf_(v.x); v.y = siluf_(v.y); v.z = siluf_(v.z); v.w = siluf_(v.w);
        *(float4*)&zs[(size_t)row*120 + (c0-120)] = v;
      }
    }
  }
}

// =============== depthwise causal conv1d (4 taps) + silu, float4 ===============
__global__ __launch_bounds__(256) void k_conv1d(
    const float* __restrict__ xin, const float* __restrict__ cw, const float* __restrict__ cb,
    float* __restrict__ xc)
{
  int g = blockIdx.x*256 + threadIdx.x;          // one float4 group of d
  if (g >= BATCH*LSEQ*30) return;
  int q = g % 30;
  int l = (g / 30) % LSEQ;
  int b = g / (30*LSEQ);
  int d0 = q*4;
  float4 acc = *(const float4*)&cb[d0];
  #pragma unroll
  for (int k = 0; k < 4; k++){
    int ll = l - 3 + k;
    if (ll >= 0){
      float4 xv = *(const float4*)&xin[((size_t)b*LSEQ+ll)*DI + d0];
      // weights: taps for d0..d0+3 at tap k -> cw[(d0+j)*4 + k]
      acc.x += cw[(d0+0)*4+k] * xv.x;
      acc.y += cw[(d0+1)*4+k] * xv.y;
      acc.z += cw[(d0+2)*4+k] * xv.z;
      acc.w += cw[(d0+3)*4+k] * xv.w;
    }
  }
  acc.x = siluf_(acc.x); acc.y = siluf_(acc.y); acc.z = siluf_(acc.z); acc.w = siluf_(acc.w);
  *(float4*)&xc[((size_t)b*LSEQ+l)*DI + d0] = acc;
}

// =============== x_proj (120->36) + dt_proj + softplus, 64-row tiled ===============
__global__ __launch_bounds__(256) void k_xproj(
    const float* __restrict__ xc, const float* __restrict__ xpw,
    const float* __restrict__ dtw, const float* __restrict__ dtb,
    float* __restrict__ delta, float* __restrict__ BC)
{
  __shared__ float AL[64*124];
  __shared__ float WxT[120*36];
  __shared__ float Wd5[120*5];
  __shared__ float bdL[120];
  __shared__ float dtsh[64*4];
  const int tid = threadIdx.x;
  const int row0 = blockIdx.x*64;
  for (int i = tid; i < 36*120; i += 256){ int o=i/120, k=i%120; WxT[k*36+o] = xpw[i]; }
  for (int i = tid; i < 480; i += 256){ int d=i/4, r=i%4; Wd5[d*5+r] = dtw[i]; }
  for (int i = tid; i < 120; i += 256) bdL[i] = dtb[i];
  for (int i = tid; i < 64*120; i += 256){
    int r = i/120, c = i%120;
    AL[r*124 + c] = xc[((size_t)row0 + r)*120 + c];
  }
  __syncthreads();
  if (tid < 144){
    const int cg = tid % 9, rg = tid / 9;
    float acc[4][4];
    #pragma unroll
    for (int r = 0; r < 4; r++){ acc[r][0]=0.f; acc[r][1]=0.f; acc[r][2]=0.f; acc[r][3]=0.f; }
    for (int kg = 0; kg < 30; kg++){
      int k = kg*4;
      float4 b0 = *(const float4*)&WxT[(k+0)*36 + cg*4];
      float4 b1 = *(const float4*)&WxT[(k+1)*36 + cg*4];
      float4 b2 = *(const float4*)&WxT[(k+2)*36 + cg*4];
      float4 b3 = *(const float4*)&WxT[(k+3)*36 + cg*4];
      #pragma unroll
      for (int r = 0; r < 4; r++){
        float4 a = *(const float4*)&AL[(rg*4+r)*124 + k];
        acc[r][0] += a.x*b0.x + a.y*b1.x + a.z*b2.x + a.w*b3.x;
        acc[r][1] += a.x*b0.y + a.y*b1.y + a.z*b2.y + a.w*b3.y;
        acc[r][2] += a.x*b0.z + a.y*b1.z + a.z*b2.z + a.w*b3.z;
        acc[r][3] += a.x*b0.w + a.y*b1.w + a.z*b2.w + a.w*b3.w;
      }
    }
    #pragma unroll
    for (int r = 0; r < 4; r++){
      int row = rg*4 + r;
      float4 v; v.x=acc[r][0]; v.y=acc[r][1]; v.z=acc[r][2]; v.w=acc[r][3];
      if (cg == 0) *(float4*)&dtsh[row*4] = v;
      else         *(float4*)&BC[((size_t)row0 + row)*32 + (cg*4 - 4)] = v;
    }
  }
  __syncthreads();
  for (int i = tid; i < 64*120; i += 256){
    int row = i/120, d = i%120;
    float4 t = *(const float4*)&dtsh[row*4];
    float acc = bdL[d] + t.x*Wd5[d*5] + t.y*Wd5[d*5+1] + t.z*Wd5[d*5+2] + t.w*Wd5[d*5+3];
    delta[((size_t)row0 + row)*120 + d] = softplusf_(acc);
  }
}

// =============== scan pass 1: per-chunk (prod dA, h_end | h0=0) ===============
__global__ __launch_bounds__(128) void k_scan1(
    const float* __restrict__ delta, const float* __restrict__ xc,
    const float* __restrict__ BC, const float* __restrict__ A_log,
    float* __restrict__ ap, float* __restrict__ he)
{
  __shared__ float Bl[TCH*16];
  const int tid = threadIdx.x;
  const int c = blockIdx.x % NCH, b = blockIdx.x / NCH;
  const size_t rowbase = (size_t)b*LSEQ + (size_t)c*TCH;
  for (int i = tid; i < TCH*16; i += 128){
    int t = i >> 4, n = i & 15;
    Bl[i] = BC[(rowbase + t)*32 + n];
  }
  __syncthreads();
  const int d = tid;
  if (d >= DI) return;
  float A2[16], h[16];
  #pragma unroll
  for (int n = 0; n < 16; n++){
    A2[n] = -__expf(A_log[d*16+n]) * 1.44269504f;
    h[n] = 0.f;
  }
  bool fastp = true;
  #pragma unroll
  for (int n = 1; n < 16; n++)
    fastp = fastp && (fabsf(A2[n] - (n+1)*A2[0]) <= 1e-4f*fabsf(A2[n]));
  int base = (c*BATCH + b)*(DI*16) + d*16;
  if (fastp){
    float P = 1.f;
    const float A20 = A2[0];
    for (int t = 0; t < TCH; t++){
      float del = delta[(rowbase+t)*DI + d];
      float xcv = xc[(rowbase+t)*DI + d];
      float dx = del * xcv;
      float r = exp2f(del * A20);
      P *= r;
      float dA[16]; powers16(r, dA);
      float4 b0 = *(const float4*)&Bl[t*16+0];
      float4 b1 = *(const float4*)&Bl[t*16+4];
      float4 b2 = *(const float4*)&Bl[t*16+8];
      float4 b3 = *(const float4*)&Bl[t*16+12];
      h[0]=dA[0]*h[0]+dx*b0.x;  h[1]=dA[1]*h[1]+dx*b0.y;  h[2]=dA[2]*h[2]+dx*b0.z;  h[3]=dA[3]*h[3]+dx*b0.w;
      h[4]=dA[4]*h[4]+dx*b1.x;  h[5]=dA[5]*h[5]+dx*b1.y;  h[6]=dA[6]*h[6]+dx*b1.z;  h[7]=dA[7]*h[7]+dx*b1.w;
      h[8]=dA[8]*h[8]+dx*b2.x;  h[9]=dA[9]*h[9]+dx*b2.y;  h[10]=dA[10]*h[10]+dx*b2.z; h[11]=dA[11]*h[11]+dx*b2.w;
      h[12]=dA[12]*h[12]+dx*b3.x; h[13]=dA[13]*h[13]+dx*b3.y; h[14]=dA[14]*h[14]+dx*b3.z; h[15]=dA[15]*h[15]+dx*b3.w;
    }
    float apv[16]; powers16(P, apv);
    #pragma unroll
    for (int n = 0; n < 16; n++){ ap[base+n] = apv[n]; he[base+n] = h[n]; }
  } else {
    float apv[16];
    #pragma unroll
    for (int n = 0; n < 16; n++) apv[n] = 1.f;
    for (int t = 0; t < TCH; t++){
      float del = delta[(rowbase+t)*DI + d];
      float xcv = xc[(rowbase+t)*DI + d];
      float dx = del * xcv;
      #pragma unroll
      for (int n = 0; n < 16; n++){
        float dA = exp2f(del * A2[n]);
        apv[n] *= dA;
        h[n] = dA*h[n] + dx*Bl[t*16+n];
      }
    }
    #pragma unroll
    for (int n = 0; n < 16; n++){ ap[base+n] = apv[n]; he[base+n] = h[n]; }
  }
}

// =============== scan pass 2: scan over chunks ===============
__global__ __launch_bounds__(256) void k_scan2(float* __restrict__ ap, const float* __restrict__ he)
{
  int g = blockIdx.x*256 + threadIdx.x;
  if (g >= BATCH*DI*16) return;
  float H = 0.f;
  const int stride = BATCH*DI*16;
  int idx = g;
  #pragma unroll 4
  for (int c = 0; c < NCH; c++){
    float a = ap[idx];
    float hend = he[idx];
    ap[idx] = H;
    H = a*H + hend;
    idx += stride;
  }
}

// =============== scan pass 3: replay + fuse D*xc and silu(z) gate ===============
__global__ __launch_bounds__(128) void k_scan3(
    const float* __restrict__ delta, const float* __restrict__ xc,
    const float* __restrict__ BC, const float* __restrict__ zs,
    const float* __restrict__ h0, const float* __restrict__ A_log,
    const float* __restrict__ Dsk, float* __restrict__ y)
{
  __shared__ float BCl[TCH*32];
  const int tid = threadIdx.x;
  const int c = blockIdx.x % NCH, b = blockIdx.x / NCH;
  const size_t rowbase = (size_t)b*LSEQ + (size_t)c*TCH;
  for (int i = tid; i < TCH*32; i += 128)
    BCl[i] = BC[rowbase*32 + i];
  __syncthreads();
  const int d = tid;
  if (d >= DI) return;
  float A2[16], h[16];
  int base = (c*BATCH + b)*(DI*16) + d*16;
  #pragma unroll
  for (int n = 0; n < 16; n++){
    A2[n] = -__expf(A_log[d*16+n]) * 1.44269504f;
    h[n] = h0[base+n];
  }
  bool fastp = true;
  #pragma unroll
  for (int n = 1; n < 16; n++)
    fastp = fastp && (fabsf(A2[n] - (n+1)*A2[0]) <= 1e-4f*fabsf(A2[n]));
  float Dv = Dsk[d];
  if (fastp){
    const float A20 = A2[0];
    for (int t = 0; t < TCH; t++){
      float del = delta[(rowbase+t)*DI + d];
      float xcv = xc[(rowbase+t)*DI + d];
      float zv  = zs[(rowbase+t)*DI + d];
      float dx = del * xcv;
      float r = exp2f(del * A20);
      float dA[16]; powers16(r, dA);
      float4 b0 = *(const float4*)&BCl[t*32+0];
      float4 b1 = *(const float4*)&BCl[t*32+4];
      float4 b2 = *(const float4*)&BCl[t*32+8];
      float4 b3 = *(const float4*)&BCl[t*32+12];
      float4 c0 = *(const float4*)&BCl[t*32+16];
      float4 c1 = *(const float4*)&BCl[t*32+20];
      float4 c2 = *(const float4*)&BCl[t*32+24];
      float4 c3 = *(const float4*)&BCl[t*32+28];
      h[0]=dA[0]*h[0]+dx*b0.x;  h[1]=dA[1]*h[1]+dx*b0.y;  h[2]=dA[2]*h[2]+dx*b0.z;  h[3]=dA[3]*h[3]+dx*b0.w;
      h[4]=dA[4]*h[4]+dx*b1.x;  h[5]=dA[5]*h[5]+dx*b1.y;  h[6]=dA[6]*h[6]+dx*b1.z;  h[7]=dA[7]*h[7]+dx*b1.w;
      h[8]=dA[8]*h[8]+dx*b2.x;  h[9]=dA[9]*h[9]+dx*b2.y;  h[10]=dA[10]*h[10]+dx*b2.z; h[11]=dA[11]*h[11]+dx*b2.w;
      h[12]=dA[12]*h[12]+dx*b3.x; h[13]=dA[13]*h[13]+dx*b3.y; h[14]=dA[14]*h[14]+dx*b3.z; h[15]=dA[15]*h[15]+dx*b3.w;
      float acc = h[0]*c0.x + h[1]*c0.y + h[2]*c0.z + h[3]*c0.w
                + h[4]*c1.x + h[5]*c1.y + h[6]*c1.z + h[7]*c1.w
                + h[8]*c2.x + h[9]*c2.y + h[10]*c2.z + h[11]*c2.w
                + h[12]*c3.x + h[13]*c3.y + h[14]*c3.z + h[15]*c3.w;
      y[(rowbase+t)*DI + d] = (acc + Dv*xcv) * zv;
    }
  } else {
    for (int t = 0; t < TCH; t++){
      float del = delta[(rowbase+t)*DI + d];
      float xcv = xc[(rowbase+t)*DI + d];
      float zv  = zs[(rowbase+t)*DI + d];
      float dx = del * xcv;
      float acc = 0.f;
      #pragma unroll
      for (int n = 0; n < 16; n++){
        float dA = exp2f(del * A2[n]);
        h[n] = dA*h[n] + dx*BCl[t*32+n];
        acc += h[n]*BCl[t*32+16+n];
      }
      y[(rowbase+t)*DI + d] = (acc + Dv*xcv) * zv;
    }
  }
}

// =============== out_proj (120 -> 60), 64-row tiled ===============
__global__ __launch_bounds__(256) void k_outproj(
    const float* __restrict__ y, const float* __restrict__ opw,
    float* __restrict__ hout)
{
  __shared__ float YL[64*124];
  __shared__ float OT[120*60];
  const int tid = threadIdx.x;
  const int row0 = blockIdx.x*64;
  for (int i = tid; i < 60*120; i += 256){ int o=i/120, k=i%120; OT[k*60+o] = opw[i]; }
  for (int i = tid; i < 64*120; i += 256){
    int r = i/120, c = i%120;
    YL[r*124 + c] = y[((size_t)row0 + r)*120 + c];
  }
  __syncthreads();
  if (tid < 240){
    const int cg = tid % 15, rg = tid / 15;
    float acc[4][4];
    #pragma unroll
    for (int r = 0; r < 4; r++){ acc[r][0]=0.f; acc[r][1]=0.f; acc[r][2]=0.f; acc[r][3]=0.f; }
    for (int kg = 0; kg < 30; kg++){
      int k = kg*4;
      float4 b0 = *(const float4*)&OT[(k+0)*60 + cg*4];
      float4 b1 = *(const float4*)&OT[(k+1)*60 + cg*4];
      float4 b2 = *(const float4*)&OT[(k+2)*60 + cg*4];
      float4 b3 = *(const float4*)&OT[(k+3)*60 + cg*4];
      #pragma unroll
      for (int r = 0; r < 4; r++){
        float4 a = *(const float4*)&YL[(rg*4+r)*124 + k];
        acc[r][0] += a.x*b0.x + a.y*b1.x + a.z*b2.x + a.w*b3.x;
        acc[r][1] += a.x*b0.y + a.y*b1.y + a.z*b2.y + a.w*b3.y;
        acc[r][2] += a.x*b0.z + a.y*b1.z + a.z*b2.z + a.w*b3.z;
        acc[r][3] += a.x*b0.w + a.y*b1.w + a.z*b2.w + a.w*b3.w;
      }
    }
    #pragma unroll
    for (int r = 0; r < 4; r++){
      int row = row0 + rg*4 + r;
      float4 v; v.x=acc[r][0]; v.y=acc[r][1]; v.z=acc[r][2]; v.w=acc[r][3];
      *(float4*)&hout[(size_t)row*60 + cg*4] = v;
    }
  }
}

// =============== conv2d weights: w[co][ci][3][3] -> wT64[idx][g*16+j], co=g*15+j ===============
__global__ __launch_bounds__(256) void k_wT(const float* __restrict__ w, float* __restrict__ wT64)
{
  int i = blockIdx.x*256 + threadIdx.x;
  if (i >= 540*64) return;
  int idx = i / 64, s = i % 64;
  int g = s / 16, j = s % 16;
  int ci = idx / 9, r = idx % 9;
  float v = 0.f;
  if (j < 15){
    int co = g*15 + j;
    v = w[((size_t)co*60 + ci)*9 + r];
  }
  wT64[i] = v;
}

// =============== 3x3 SAME conv2d + bias + residual ===============
// 64-px strip; wave -> 15 couts, lane -> px. Weights via scalar loads (global).
__global__ __launch_bounds__(256) void k_conv2d(
    const float* __restrict__ hin, const float* __restrict__ wT64,
    const float* __restrict__ cb, const float* __restrict__ xres,
    float* __restrict__ out)
{
  __shared__ float tile[3*66*61];   // 48.3 KB
  const int tid = threadIdx.x;
  const int blk = blockIdx.x;
  const int xhalf = blk & 1;
  const int yy = (blk >> 1) & 127;
  const int b = blk >> 8;
  const int x0 = xhalf*64;
  for (int i = tid; i < 3*66*60; i += 256){
    int row = i / (66*60);
    int rem = i % (66*60);
    int xx = rem / 60, ci = rem % 60;
    int gy = yy - 1 + row, gx = x0 - 1 + xx;
    float v = 0.f;
    if (gy >= 0 && gy < HH && gx >= 0 && gx < WW)
      v = hin[((size_t)b*LSEQ + gy*WW + gx)*60 + ci];
    tile[(row*66 + xx)*61 + ci] = v;
  }
  __syncthreads();
  const int wave = tid >> 6, lane = tid & 63;
  const int wv16 = __builtin_amdgcn_readfirstlane(wave) * 16;
  const float* wbase = wT64 + wv16;
  float acc[15];
  #pragma unroll
  for (int j = 0; j < 15; j++) acc[j] = 0.f;
  for (int ci = 0; ci < 60; ci++){
    #pragma unroll
    for (int tap = 0; tap < 9; tap++){
      int ky = tap/3, kx = tap%3;
      float xv = tile[(ky*66 + lane + kx)*61 + ci];
      const float4* wq = (const float4*)(wbase + (size_t)(ci*9 + tap)*64);
      float4 w0 = wq[0], w1 = wq[1], w2 = wq[2], w3 = wq[3];
      acc[0]  += xv*w0.x; acc[1]  += xv*w0.y; acc[2]  += xv*w0.z; acc[3]  += xv*w0.w;
      acc[4]  += xv*w1.x; acc[5]  += xv*w1.y; acc[6]  += xv*w1.z; acc[7]  += xv*w1.w;
      acc[8]  += xv*w2.x; acc[9]  += xv*w2.y; acc[10] += xv*w2.z; acc[11] += xv*w2.w;
      acc[12] += xv*w3.x; acc[13] += xv*w3.y; acc[14] += xv*w3.z;
    }
  }
  __syncthreads();
  // transpose epilogue through LDS for coalesced stores
  float* obuf = tile;
  #pragma unroll
  for (int j = 0; j < 15; j++)
    obuf[lane*61 + wave*15 + j] = acc[j];
  __syncthreads();
  const size_t base = ((size_t)b*LSEQ + yy*WW + x0)*60;
  for (int i = tid; i < 64*60; i += 256){
    int px = i/60, co = i%60;
    out[base + i] = obuf[px*61 + co] + cb[co] + xres[base + i];
  }
}

extern "C" void kernel_launch(void* const* d_in, const int* in_sizes, int n_in,
                              void* d_out, int out_size, void* d_ws, size_t ws_size,
                              hipStream_t stream)
{
  const float* x      = (const float*)d_in[0];
  const float* ln_w   = (const float*)d_in[1];
  const float* ln_b   = (const float*)d_in[2];
  const float* ipw    = (const float*)d_in[3];
  const float* cw     = (const float*)d_in[4];
  const float* cb1    = (const float*)d_in[5];
  const float* xpw    = (const float*)d_in[6];
  const float* dtw    = (const float*)d_in[7];
  const float* dtb    = (const float*)d_in[8];
  const float* A_log  = (const float*)d_in[9];
  const float* Dsk    = (const float*)d_in[10];
  const float* opw    = (const float*)d_in[11];
  const float* c2w    = (const float*)d_in[12];
  const float* c2b    = (const float*)d_in[13];
  float* out = (float*)d_out;

  float* ws = (float*)d_ws;
  size_t off = 0;
  float* xin   = ws + off; off += (size_t)BATCH*LSEQ*DI;
  float* zsb   = ws + off; off += (size_t)BATCH*LSEQ*DI;
  float* xcb   = ws + off; off += (size_t)BATCH*LSEQ*DI;
  float* dlt   = ws + off; off += (size_t)BATCH*LSEQ*DI;
  float* BC    = ws + off; off += (size_t)BATCH*LSEQ*32;
  float* apb   = ws + off; off += (size_t)NCH*BATCH*DI*16;
  float* heb   = ws + off; off += (size_t)NCH*BATCH*DI*16;
  float* hcur  = ws + off; off += (size_t)BATCH*LSEQ*DM;
  float* wTb   = ws + off; off += (size_t)540*64;
  float* ybuf  = xin;

  const int rows = BATCH*LSEQ;
  for (int layer = 0; layer < 2; layer++){
    const float* src = (layer == 0) ? x : hcur;
    k_ln_inproj<<<rows/64, 256, 0, stream>>>(src, ln_w + layer*DM, ln_b + layer*DM,
                                             ipw + (size_t)layer*240*DM, xin, zsb);
    k_conv1d<<<(rows*30+255)/256, 256, 0, stream>>>(xin, cw + layer*DI*4, cb1 + layer*DI, xcb);
    k_xproj<<<rows/64, 256, 0, stream>>>(xcb, xpw + (size_t)layer*36*DI, dtw + (size_t)layer*DI*4,
                                         dtb + layer*DI, dlt, BC);
    k_scan1<<<BATCH*NCH, 128, 0, stream>>>(dlt, xcb, BC, A_log + (size_t)layer*DI*16, apb, heb);
    k_scan2<<<(BATCH*DI*16+255)/256, 256, 0, stream>>>(apb, heb);
    k_scan3<<<BATCH*NCH, 128, 0, stream>>>(dlt, xcb, BC, zsb, apb, A_log + (size_t)layer*DI*16,
                                           Dsk + layer*DI, ybuf);
    k_outproj<<<rows/64, 256, 0, stream>>>(ybuf, opw + (size_t)layer*DM*DI, hcur);
  }
  k_wT<<<(540*64+255)/256, 256, 0, stream>>>(c2w, wTb);
  k_conv2d<<<BATCH*HH*2, 256, 0, stream>>>(hcur, wTb, c2b, x, out);
}

// Round 6
// 538.568 us; speedup vs baseline: 1.5833x; 1.1155x over previous
//
#include <hip/hip_runtime.h>
#include <math.h>

#define BATCH 2
#define LSEQ 16384
#define DM 60
#define DI 120
#define NCH 512
#define TCH 32    // LSEQ / NCH
#define HH 128
#define WW 128

typedef __attribute__((ext_vector_type(8))) short bhalf8;
typedef __attribute__((ext_vector_type(4))) float f32x4;

__device__ __forceinline__ float sigmoidf_(float x){ return 1.0f/(1.0f + __expf(-x)); }
__device__ __forceinline__ float siluf_(float x){ return x * sigmoidf_(x); }
__device__ __forceinline__ float softplusf_(float x){ return (x > 20.0f) ? x : log1pf(__expf(x)); }
__device__ __forceinline__ short f2b(float f){   // RNE fp32->bf16 (finite inputs)
  union{float f; unsigned u;} v; v.f = f;
  unsigned r = (v.u + 0x7fffu + ((v.u >> 16) & 1u)) >> 16;
  return (short)r;
}

__device__ __forceinline__ float waveReduceSum(float v){
  #pragma unroll
  for (int off = 32; off > 0; off >>= 1) v += __shfl_xor(v, off, 64);
  return v;
}

// powers: dA[n] = r^(n+1), log-depth tree
__device__ __forceinline__ void powers16(float r, float* dA){
  dA[0] = r;
  #pragma unroll
  for (int n = 1; n < 16; n++) dA[n] = dA[(n-1)>>1] * dA[n>>1];
}

// =============== LN + in_proj (60 -> 240) as 64-row tiled GEMM ===============
__global__ __launch_bounds__(256) void k_ln_inproj(
    const float* __restrict__ src,
    const float* __restrict__ ln_w, const float* __restrict__ ln_b,
    const float* __restrict__ ipw,
    float* __restrict__ xin, float* __restrict__ zs)
{
  __shared__ float WtB[60*244];
  __shared__ float hnL[64*64];
  const int tid = threadIdx.x;
  for (int i = tid; i < 240*60; i += 256){
    int o = i/60, k = i%60;
    WtB[k*244 + o] = ipw[i];
  }
  const int wave = tid >> 6, lane = tid & 63;
  const int row0 = blockIdx.x*64;
  float lw = (lane < 60) ? ln_w[lane] : 0.f;
  float lb = (lane < 60) ? ln_b[lane] : 0.f;
  for (int rr = 0; rr < 16; rr++){
    int row = row0 + wave*16 + rr;
    float v = (lane < 60) ? src[(size_t)row*60 + lane] : 0.f;
    float mu = waveReduceSum(v) * (1.0f/60.0f);
    float dv = (lane < 60) ? (v - mu) : 0.f;
    float var = waveReduceSum(dv*dv) * (1.0f/60.0f);
    float rs = rsqrtf(var + 1e-5f);
    if (lane < 60) hnL[(wave*16+rr)*64 + lane] = dv*rs*lw + lb;
  }
  __syncthreads();
  if (tid < 240){
    const int cg = tid % 60, rg = tid / 60;
    float acc[16][4];
    #pragma unroll
    for (int r = 0; r < 16; r++){ acc[r][0]=0.f; acc[r][1]=0.f; acc[r][2]=0.f; acc[r][3]=0.f; }
    for (int kg = 0; kg < 15; kg++){
      int k = kg*4;
      float4 b0 = *(const float4*)&WtB[(k+0)*244 + cg*4];
      float4 b1 = *(const float4*)&WtB[(k+1)*244 + cg*4];
      float4 b2 = *(const float4*)&WtB[(k+2)*244 + cg*4];
      float4 b3 = *(const float4*)&WtB[(k+3)*244 + cg*4];
      #pragma unroll
      for (int r = 0; r < 16; r++){
        float4 a = *(const float4*)&hnL[(rg*16+r)*64 + k];
        acc[r][0] += a.x*b0.x + a.y*b1.x + a.z*b2.x + a.w*b3.x;
        acc[r][1] += a.x*b0.y + a.y*b1.y + a.z*b2.y + a.w*b3.y;
        acc[r][2] += a.x*b0.z + a.y*b1.z + a.z*b2.z + a.w*b3.z;
        acc[r][3] += a.x*b0.w + a.y*b1.w + a.z*b2.w + a.w*b3.w;
      }
    }
    const int c0 = cg*4;
    #pragma unroll
    for (int r = 0; r < 16; r++){
      int row = row0 + rg*16 + r;
      float4 v; v.x=acc[r][0]; v.y=acc[r][1]; v.z=acc[r][2]; v.w=acc[r][3];
      if (c0 < 120){
        *(float4*)&xin[(size_t)row*120 + c0] = v;
      } else {
        v.x = siluf_(v.x); v.y = siluf_(v.y); v.z = siluf_(v.z); v.w = siluf_(v.w);
        *(float4*)&zs[(size_t)row*120 + (c0-120)] = v;
      }
    }
  }
}

// =============== fused conv1d + x_proj + dt_proj + softplus, 64-row tiled ===============
__global__ __launch_bounds__(256) void k_xprojc(
    const float* __restrict__ xin,
    const float* __restrict__ cw, const float* __restrict__ cb,
    const float* __restrict__ xpw,
    const float* __restrict__ dtw, const float* __restrict__ dtb,
    float* __restrict__ xc, float* __restrict__ delta, float* __restrict__ BC)
{
  __shared__ float XT[67*124];    // rows row0-3 .. row0+63; reused as AL after conv
  __shared__ float WxT[120*36];
  __shared__ float Wd5[120*5];
  __shared__ float cwL[120*4];
  __shared__ float bdL[120];
  __shared__ float cbL[120];
  __shared__ float dtsh[64*4];
  const int tid = threadIdx.x;
  const int row0 = blockIdx.x*64;
  const int seq0 = (row0 / LSEQ) * LSEQ;   // batch start row (causal pad boundary)
  for (int i = tid; i < 36*120; i += 256){ int o=i/120, k=i%120; WxT[k*36+o] = xpw[i]; }
  for (int i = tid; i < 480; i += 256){ Wd5[(i/4)*5 + (i%4)] = dtw[i]; cwL[i] = cw[i]; }
  for (int i = tid; i < 120; i += 256){ bdL[i] = dtb[i]; cbL[i] = cb[i]; }
  for (int i = tid; i < 67*120; i += 256){
    int r = i/120, c = i%120;
    int grow = row0 - 3 + r;
    XT[r*124 + c] = (grow >= seq0) ? xin[(size_t)grow*120 + c] : 0.f;
  }
  __syncthreads();
  float xcv[30];
  #pragma unroll
  for (int j = 0; j < 30; j++){
    int i = tid + j*256;
    int r = i/120, c = i%120;
    float acc = cbL[c];
    #pragma unroll
    for (int k = 0; k < 4; k++) acc += cwL[c*4+k] * XT[(r+k)*124 + c];
    acc = siluf_(acc);
    xcv[j] = acc;
    xc[(size_t)(row0 + r)*120 + c] = acc;
  }
  __syncthreads();
  #pragma unroll
  for (int j = 0; j < 30; j++){
    int i = tid + j*256;
    int r = i/120, c = i%120;
    XT[r*124 + c] = xcv[j];
  }
  __syncthreads();
  if (tid < 144){
    const int cg = tid % 9, rg = tid / 9;
    float acc[4][4];
    #pragma unroll
    for (int r = 0; r < 4; r++){ acc[r][0]=0.f; acc[r][1]=0.f; acc[r][2]=0.f; acc[r][3]=0.f; }
    for (int kg = 0; kg < 30; kg++){
      int k = kg*4;
      float4 b0 = *(const float4*)&WxT[(k+0)*36 + cg*4];
      float4 b1 = *(const float4*)&WxT[(k+1)*36 + cg*4];
      float4 b2 = *(const float4*)&WxT[(k+2)*36 + cg*4];
      float4 b3 = *(const float4*)&WxT[(k+3)*36 + cg*4];
      #pragma unroll
      for (int r = 0; r < 4; r++){
        float4 a = *(const float4*)&XT[(rg*4+r)*124 + k];
        acc[r][0] += a.x*b0.x + a.y*b1.x + a.z*b2.x + a.w*b3.x;
        acc[r][1] += a.x*b0.y + a.y*b1.y + a.z*b2.y + a.w*b3.y;
        acc[r][2] += a.x*b0.z + a.y*b1.z + a.z*b2.z + a.w*b3.z;
        acc[r][3] += a.x*b0.w + a.y*b1.w + a.z*b2.w + a.w*b3.w;
      }
    }
    #pragma unroll
    for (int r = 0; r < 4; r++){
      int row = rg*4 + r;
      float4 v; v.x=acc[r][0]; v.y=acc[r][1]; v.z=acc[r][2]; v.w=acc[r][3];
      if (cg == 0) *(float4*)&dtsh[row*4] = v;
      else         *(float4*)&BC[((size_t)row0 + row)*32 + (cg*4 - 4)] = v;
    }
  }
  __syncthreads();
  #pragma unroll
  for (int j = 0; j < 30; j++){
    int i = tid + j*256;
    int row = i/120, d = i%120;
    float4 t = *(const float4*)&dtsh[row*4];
    float acc = bdL[d] + t.x*Wd5[d*5] + t.y*Wd5[d*5+1] + t.z*Wd5[d*5+2] + t.w*Wd5[d*5+3];
    delta[(size_t)(row0 + row)*120 + d] = softplusf_(acc);
  }
}

// =============== scan pass 1: per-chunk (prod dA, h_end | h0=0) ===============
__global__ __launch_bounds__(128) void k_scan1(
    const float* __restrict__ delta, const float* __restrict__ xc,
    const float* __restrict__ BC, const float* __restrict__ A_log,
    float* __restrict__ ap, float* __restrict__ he)
{
  __shared__ float Bl[TCH*16];
  const int tid = threadIdx.x;
  const int c = blockIdx.x % NCH, b = blockIdx.x / NCH;
  const size_t rowbase = (size_t)b*LSEQ + (size_t)c*TCH;
  for (int i = tid; i < TCH*16; i += 128){
    int t = i >> 4, n = i & 15;
    Bl[i] = BC[(rowbase + t)*32 + n];
  }
  __syncthreads();
  const int d = tid;
  if (d >= DI) return;
  float A2[16], h[16];
  #pragma unroll
  for (int n = 0; n < 16; n++){
    A2[n] = -__expf(A_log[d*16+n]) * 1.44269504f;
    h[n] = 0.f;
  }
  bool fastp = true;
  #pragma unroll
  for (int n = 1; n < 16; n++)
    fastp = fastp && (fabsf(A2[n] - (n+1)*A2[0]) <= 1e-4f*fabsf(A2[n]));
  int base = (c*BATCH + b)*(DI*16) + d*16;
  if (fastp){
    float P = 1.f;
    const float A20 = A2[0];
    for (int t = 0; t < TCH; t++){
      float del = delta[(rowbase+t)*DI + d];
      float xcv = xc[(rowbase+t)*DI + d];
      float dx = del * xcv;
      float r = exp2f(del * A20);
      P *= r;
      float dA[16]; powers16(r, dA);
      float4 b0 = *(const float4*)&Bl[t*16+0];
      float4 b1 = *(const float4*)&Bl[t*16+4];
      float4 b2 = *(const float4*)&Bl[t*16+8];
      float4 b3 = *(const float4*)&Bl[t*16+12];
      h[0]=dA[0]*h[0]+dx*b0.x;  h[1]=dA[1]*h[1]+dx*b0.y;  h[2]=dA[2]*h[2]+dx*b0.z;  h[3]=dA[3]*h[3]+dx*b0.w;
      h[4]=dA[4]*h[4]+dx*b1.x;  h[5]=dA[5]*h[5]+dx*b1.y;  h[6]=dA[6]*h[6]+dx*b1.z;  h[7]=dA[7]*h[7]+dx*b1.w;
      h[8]=dA[8]*h[8]+dx*b2.x;  h[9]=dA[9]*h[9]+dx*b2.y;  h[10]=dA[10]*h[10]+dx*b2.z; h[11]=dA[11]*h[11]+dx*b2.w;
      h[12]=dA[12]*h[12]+dx*b3.x; h[13]=dA[13]*h[13]+dx*b3.y; h[14]=dA[14]*h[14]+dx*b3.z; h[15]=dA[15]*h[15]+dx*b3.w;
    }
    float apv[16]; powers16(P, apv);
    #pragma unroll
    for (int n = 0; n < 16; n++){ ap[base+n] = apv[n]; he[base+n] = h[n]; }
  } else {
    float apv[16];
    #pragma unroll
    for (int n = 0; n < 16; n++) apv[n] = 1.f;
    for (int t = 0; t < TCH; t++){
      float del = delta[(rowbase+t)*DI + d];
      float xcv = xc[(rowbase+t)*DI + d];
      float dx = del * xcv;
      #pragma unroll
      for (int n = 0; n < 16; n++){
        float dA = exp2f(del * A2[n]);
        apv[n] *= dA;
        h[n] = dA*h[n] + dx*Bl[t*16+n];
      }
    }
    #pragma unroll
    for (int n = 0; n < 16; n++){ ap[base+n] = apv[n]; he[base+n] = h[n]; }
  }
}

// =============== scan pass 2: scan over chunks ===============
__global__ __launch_bounds__(256) void k_scan2(float* __restrict__ ap, const float* __restrict__ he)
{
  int g = blockIdx.x*256 + threadIdx.x;
  if (g >= BATCH*DI*16) return;
  float H = 0.f;
  const int stride = BATCH*DI*16;
  int idx = g;
  #pragma unroll 4
  for (int c = 0; c < NCH; c++){
    float a = ap[idx];
    float hend = he[idx];
    ap[idx] = H;
    H = a*H + hend;
    idx += stride;
  }
}

// =============== scan pass 3 + out_proj fused ===============
__global__ __launch_bounds__(128) void k_scan3o(
    const float* __restrict__ delta, const float* __restrict__ xc,
    const float* __restrict__ BC, const float* __restrict__ zs,
    const float* __restrict__ h0, const float* __restrict__ A_log,
    const float* __restrict__ Dsk, const float* __restrict__ opw,
    float* __restrict__ hout)
{
  __shared__ float BCl[TCH*32];
  __shared__ float yL[TCH*124];
  const int tid = threadIdx.x;
  const int c = blockIdx.x % NCH, b = blockIdx.x / NCH;
  const size_t rowbase = (size_t)b*LSEQ + (size_t)c*TCH;
  for (int i = tid; i < TCH*32; i += 128)
    BCl[i] = BC[rowbase*32 + i];
  __syncthreads();
  const int d = tid;
  if (d < DI){
    float A2[16], h[16];
    int base = (c*BATCH + b)*(DI*16) + d*16;
    #pragma unroll
    for (int n = 0; n < 16; n++){
      A2[n] = -__expf(A_log[d*16+n]) * 1.44269504f;
      h[n] = h0[base+n];
    }
    bool fastp = true;
    #pragma unroll
    for (int n = 1; n < 16; n++)
      fastp = fastp && (fabsf(A2[n] - (n+1)*A2[0]) <= 1e-4f*fabsf(A2[n]));
    float Dv = Dsk[d];
    if (fastp){
      const float A20 = A2[0];
      for (int t = 0; t < TCH; t++){
        float del = delta[(rowbase+t)*DI + d];
        float xcv = xc[(rowbase+t)*DI + d];
        float zv  = zs[(rowbase+t)*DI + d];
        float dx = del * xcv;
        float r = exp2f(del * A20);
        float dA[16]; powers16(r, dA);
        float4 b0 = *(const float4*)&BCl[t*32+0];
        float4 b1 = *(const float4*)&BCl[t*32+4];
        float4 b2 = *(const float4*)&BCl[t*32+8];
        float4 b3 = *(const float4*)&BCl[t*32+12];
        float4 c0 = *(const float4*)&BCl[t*32+16];
        float4 c1 = *(const float4*)&BCl[t*32+20];
        float4 c2 = *(const float4*)&BCl[t*32+24];
        float4 c3 = *(const float4*)&BCl[t*32+28];
        h[0]=dA[0]*h[0]+dx*b0.x;  h[1]=dA[1]*h[1]+dx*b0.y;  h[2]=dA[2]*h[2]+dx*b0.z;  h[3]=dA[3]*h[3]+dx*b0.w;
        h[4]=dA[4]*h[4]+dx*b1.x;  h[5]=dA[5]*h[5]+dx*b1.y;  h[6]=dA[6]*h[6]+dx*b1.z;  h[7]=dA[7]*h[7]+dx*b1.w;
        h[8]=dA[8]*h[8]+dx*b2.x;  h[9]=dA[9]*h[9]+dx*b2.y;  h[10]=dA[10]*h[10]+dx*b2.z; h[11]=dA[11]*h[11]+dx*b2.w;
        h[12]=dA[12]*h[12]+dx*b3.x; h[13]=dA[13]*h[13]+dx*b3.y; h[14]=dA[14]*h[14]+dx*b3.z; h[15]=dA[15]*h[15]+dx*b3.w;
        float acc = h[0]*c0.x + h[1]*c0.y + h[2]*c0.z + h[3]*c0.w
                  + h[4]*c1.x + h[5]*c1.y + h[6]*c1.z + h[7]*c1.w
                  + h[8]*c2.x + h[9]*c2.y + h[10]*c2.z + h[11]*c2.w
                  + h[12]*c3.x + h[13]*c3.y + h[14]*c3.z + h[15]*c3.w;
        yL[t*124 + d] = (acc + Dv*xcv) * zv;
      }
    } else {
      for (int t = 0; t < TCH; t++){
        float del = delta[(rowbase+t)*DI + d];
        float xcv = xc[(rowbase+t)*DI + d];
        float zv  = zs[(rowbase+t)*DI + d];
        float dx = del * xcv;
        float acc = 0.f;
        #pragma unroll
        for (int n = 0; n < 16; n++){
          float dA = exp2f(del * A2[n]);
          h[n] = dA*h[n] + dx*BCl[t*32+n];
          acc += h[n]*BCl[t*32+16+n];
        }
        yL[t*124 + d] = (acc + Dv*xcv) * zv;
      }
    }
  }
  __syncthreads();
  // out_proj: hout[row][o] = sum_k yL[row][k] * opw[o][k]; 4x4 per thread
  if (tid < 120){
    const int cg = tid % 15, rg = tid / 15;   // 15 col-groups x 8 row-groups
    float acc[4][4];
    #pragma unroll
    for (int r = 0; r < 4; r++){ acc[r][0]=0.f; acc[r][1]=0.f; acc[r][2]=0.f; acc[r][3]=0.f; }
    for (int kg = 0; kg < 30; kg++){
      int k = kg*4;
      float4 b0 = *(const float4*)&opw[(size_t)(cg*4+0)*120 + k];
      float4 b1 = *(const float4*)&opw[(size_t)(cg*4+1)*120 + k];
      float4 b2 = *(const float4*)&opw[(size_t)(cg*4+2)*120 + k];
      float4 b3 = *(const float4*)&opw[(size_t)(cg*4+3)*120 + k];
      #pragma unroll
      for (int r = 0; r < 4; r++){
        float4 a = *(const float4*)&yL[(rg*4+r)*124 + k];
        acc[r][0] += a.x*b0.x + a.y*b0.y + a.z*b0.z + a.w*b0.w;
        acc[r][1] += a.x*b1.x + a.y*b1.y + a.z*b1.z + a.w*b1.w;
        acc[r][2] += a.x*b2.x + a.y*b2.y + a.z*b2.z + a.w*b2.w;
        acc[r][3] += a.x*b3.x + a.y*b3.y + a.z*b3.z + a.w*b3.w;
      }
    }
    #pragma unroll
    for (int r = 0; r < 4; r++){
      float4 v; v.x=acc[r][0]; v.y=acc[r][1]; v.z=acc[r][2]; v.w=acc[r][3];
      *(float4*)&hout[(rowbase + rg*4 + r)*60 + cg*4] = v;
    }
  }
}

// =============== conv2d weight pack: w[co][ci][3][3] -> bf16 wB[tap][co64][ci64] ===============
__global__ __launch_bounds__(256) void k_wB(const float* __restrict__ w, short* __restrict__ wB)
{
  int i = blockIdx.x*256 + threadIdx.x;
  if (i >= 9*64*64) return;
  int ci = i & 63, co = (i >> 6) & 63, tap = i >> 12;
  float v = 0.f;
  if (co < 60 && ci < 60) v = w[((size_t)co*60 + ci)*9 + tap];
  wB[i] = f2b(v);
}

// =============== 3x3 SAME conv2d via bf16 MFMA + bias + residual ===============
__global__ __launch_bounds__(256) void k_conv2d(
    const float* __restrict__ hin, const short* __restrict__ wB,
    const float* __restrict__ cb, const float* __restrict__ xres,
    float* __restrict__ out)
{
  __shared__ short tile[3*66*72];   // bf16, ci padded to 72 (16B-aligned rows)
  const int tid = threadIdx.x;
  const int blk = blockIdx.x;
  const int xhalf = blk & 1;
  const int yy = (blk >> 1) & 127;
  const int b = blk >> 8;
  const int x0 = xhalf*64;
  for (int i = tid; i < 3*66*72; i += 256){
    int ci = i % 72;
    int xx = (i / 72) % 66;
    int row = i / (72*66);
    int gy = yy - 1 + row, gx = x0 - 1 + xx;
    float v = 0.f;
    if (ci < 60 && gy >= 0 && gy < HH && gx >= 0 && gx < WW)
      v = hin[((size_t)b*LSEQ + gy*WW + gx)*60 + ci];
    tile[i] = f2b(v);
  }
  __syncthreads();
  const int wave = tid >> 6, lane = tid & 63;
  const int m = lane & 15, quad = lane >> 4;
  f32x4 acc0 = {0.f,0.f,0.f,0.f}, acc1 = {0.f,0.f,0.f,0.f};
  f32x4 acc2 = {0.f,0.f,0.f,0.f}, acc3 = {0.f,0.f,0.f,0.f};
  #pragma unroll
  for (int tap = 0; tap < 9; tap++){
    const int ky = tap/3, kx = tap%3;
    const short* arow = &tile[(ky*66 + wave*16 + m + kx)*72];
    const short* brow = wB + tap*4096;
    #pragma unroll
    for (int kh = 0; kh < 2; kh++){
      const int k0 = kh*32 + quad*8;
      bhalf8 a = *(const bhalf8*)(arow + k0);
      bhalf8 b0 = *(const bhalf8*)(brow + (0*16 + m)*64 + k0);
      bhalf8 b1 = *(const bhalf8*)(brow + (1*16 + m)*64 + k0);
      bhalf8 b2 = *(const bhalf8*)(brow + (2*16 + m)*64 + k0);
      bhalf8 b3 = *(const bhalf8*)(brow + (3*16 + m)*64 + k0);
      acc0 = __builtin_amdgcn_mfma_f32_16x16x32_bf16(a, b0, acc0, 0, 0, 0);
      acc1 = __builtin_amdgcn_mfma_f32_16x16x32_bf16(a, b1, acc1, 0, 0, 0);
      acc2 = __builtin_amdgcn_mfma_f32_16x16x32_bf16(a, b2, acc2, 0, 0, 0);
      acc3 = __builtin_amdgcn_mfma_f32_16x16x32_bf16(a, b3, acc3, 0, 0, 0);
    }
  }
  // D layout: row(px within 16) = quad*4 + reg, col(co) = ntile*16 + m
  const size_t rowb = (size_t)b*LSEQ + yy*WW + x0;
  f32x4 accs[4] = {acc0, acc1, acc2, acc3};
  #pragma unroll
  for (int nt = 0; nt < 4; nt++){
    int co = nt*16 + m;
    if (co < 60){
      float bias = cb[co];
      #pragma unroll
      for (int reg = 0; reg < 4; reg++){
        int px = wave*16 + quad*4 + reg;
        size_t o = (rowb + px)*60 + co;
        out[o] = accs[nt][reg] + bias + xres[o];
      }
    }
  }
}

extern "C" void kernel_launch(void* const* d_in, const int* in_sizes, int n_in,
                              void* d_out, int out_size, void* d_ws, size_t ws_size,
                              hipStream_t stream)
{
  const float* x      = (const float*)d_in[0];
  const float* ln_w   = (const float*)d_in[1];
  const float* ln_b   = (const float*)d_in[2];
  const float* ipw    = (const float*)d_in[3];
  const float* cw     = (const float*)d_in[4];
  const float* cb1    = (const float*)d_in[5];
  const float* xpw    = (const float*)d_in[6];
  const float* dtw    = (const float*)d_in[7];
  const float* dtb    = (const float*)d_in[8];
  const float* A_log  = (const float*)d_in[9];
  const float* Dsk    = (const float*)d_in[10];
  const float* opw    = (const float*)d_in[11];
  const float* c2w    = (const float*)d_in[12];
  const float* c2b    = (const float*)d_in[13];
  float* out = (float*)d_out;

  float* ws = (float*)d_ws;
  size_t off = 0;
  float* xin   = ws + off; off += (size_t)BATCH*LSEQ*DI;
  float* zsb   = ws + off; off += (size_t)BATCH*LSEQ*DI;
  float* xcb   = ws + off; off += (size_t)BATCH*LSEQ*DI;
  float* dlt   = ws + off; off += (size_t)BATCH*LSEQ*DI;
  float* BC    = ws + off; off += (size_t)BATCH*LSEQ*32;
  float* apb   = ws + off; off += (size_t)NCH*BATCH*DI*16;
  float* heb   = ws + off; off += (size_t)NCH*BATCH*DI*16;
  float* hcur  = ws + off; off += (size_t)BATCH*LSEQ*DM;
  short* wBb   = (short*)(ws + off); off += (size_t)9*64*64/2;

  const int rows = BATCH*LSEQ;
  for (int layer = 0; layer < 2; layer++){
    const float* src = (layer == 0) ? x : hcur;
    k_ln_inproj<<<rows/64, 256, 0, stream>>>(src, ln_w + layer*DM, ln_b + layer*DM,
                                             ipw + (size_t)layer*240*DM, xin, zsb);
    k_xprojc<<<rows/64, 256, 0, stream>>>(xin, cw + layer*DI*4, cb1 + layer*DI,
                                          xpw + (size_t)layer*36*DI, dtw + (size_t)layer*DI*4,
                                          dtb + layer*DI, xcb, dlt, BC);
    k_scan1<<<BATCH*NCH, 128, 0, stream>>>(dlt, xcb, BC, A_log + (size_t)layer*DI*16, apb, heb);
    k_scan2<<<(BATCH*DI*16+255)/256, 256, 0, stream>>>(apb, heb);
    k_scan3o<<<BATCH*NCH, 128, 0, stream>>>(dlt, xcb, BC, zsb, apb, A_log + (size_t)layer*DI*16,
                                            Dsk + layer*DI, opw + (size_t)layer*DM*DI, hcur);
  }
  k_wB<<<(9*64*64+255)/256, 256, 0, stream>>>(c2w, wBb);
  k_conv2d<<<BATCH*HH*2, 256, 0, stream>>>(hcur, wBb, c2b, x, out);
}

// Round 7
// 428.823 us; speedup vs baseline: 1.9885x; 1.2559x over previous
//
#include <hip/hip_runtime.h>
#include <math.h>

#define BATCH 2
#define LSEQ 16384
#define DM 60
#define DI 120
#define NCH 512
#define TCH 32    // LSEQ / NCH
#define HH 128
#define WW 128

typedef __attribute__((ext_vector_type(8))) short bhalf8;
typedef __attribute__((ext_vector_type(4))) float f32x4;

__device__ __forceinline__ float sigmoidf_(float x){ return 1.0f/(1.0f + __expf(-x)); }
__device__ __forceinline__ float siluf_(float x){ return x * sigmoidf_(x); }
__device__ __forceinline__ float softplusf_(float x){ return (x > 20.0f) ? x : log1pf(__expf(x)); }
__device__ __forceinline__ short f2b(float f){   // RNE fp32->bf16 (finite inputs)
  union{float f; unsigned u;} v; v.f = f;
  unsigned r = (v.u + 0x7fffu + ((v.u >> 16) & 1u)) >> 16;
  return (short)r;
}

__device__ __forceinline__ float waveReduceSum(float v){
  #pragma unroll
  for (int off = 32; off > 0; off >>= 1) v += __shfl_xor(v, off, 64);
  return v;
}

// powers: dA[n] = r^(n+1), log-depth tree
__device__ __forceinline__ void powers16(float r, float* dA){
  dA[0] = r;
  #pragma unroll
  for (int n = 1; n < 16; n++) dA[n] = dA[(n-1)>>1] * dA[n>>1];
}

// =============== LN + in_proj (60 -> 240) as 64-row tiled GEMM ===============
__global__ __launch_bounds__(256) void k_ln_inproj(
    const float* __restrict__ src,
    const float* __restrict__ ln_w, const float* __restrict__ ln_b,
    const float* __restrict__ ipw,
    float* __restrict__ xin, float* __restrict__ zs)
{
  __shared__ float WtB[60*244];
  __shared__ float hnL[64*64];
  const int tid = threadIdx.x;
  for (int i = tid; i < 240*60; i += 256){
    int o = i/60, k = i%60;
    WtB[k*244 + o] = ipw[i];
  }
  const int wave = tid >> 6, lane = tid & 63;
  const int row0 = blockIdx.x*64;
  float lw = (lane < 60) ? ln_w[lane] : 0.f;
  float lb = (lane < 60) ? ln_b[lane] : 0.f;
  for (int rr = 0; rr < 16; rr++){
    int row = row0 + wave*16 + rr;
    float v = (lane < 60) ? src[(size_t)row*60 + lane] : 0.f;
    float mu = waveReduceSum(v) * (1.0f/60.0f);
    float dv = (lane < 60) ? (v - mu) : 0.f;
    float var = waveReduceSum(dv*dv) * (1.0f/60.0f);
    float rs = rsqrtf(var + 1e-5f);
    if (lane < 60) hnL[(wave*16+rr)*64 + lane] = dv*rs*lw + lb;
  }
  __syncthreads();
  if (tid < 240){
    const int cg = tid % 60, rg = tid / 60;
    float acc[16][4];
    #pragma unroll
    for (int r = 0; r < 16; r++){ acc[r][0]=0.f; acc[r][1]=0.f; acc[r][2]=0.f; acc[r][3]=0.f; }
    for (int kg = 0; kg < 15; kg++){
      int k = kg*4;
      float4 b0 = *(const float4*)&WtB[(k+0)*244 + cg*4];
      float4 b1 = *(const float4*)&WtB[(k+1)*244 + cg*4];
      float4 b2 = *(const float4*)&WtB[(k+2)*244 + cg*4];
      float4 b3 = *(const float4*)&WtB[(k+3)*244 + cg*4];
      #pragma unroll
      for (int r = 0; r < 16; r++){
        float4 a = *(const float4*)&hnL[(rg*16+r)*64 + k];
        acc[r][0] += a.x*b0.x + a.y*b1.x + a.z*b2.x + a.w*b3.x;
        acc[r][1] += a.x*b0.y + a.y*b1.y + a.z*b2.y + a.w*b3.y;
        acc[r][2] += a.x*b0.z + a.y*b1.z + a.z*b2.z + a.w*b3.z;
        acc[r][3] += a.x*b0.w + a.y*b1.w + a.z*b2.w + a.w*b3.w;
      }
    }
    const int c0 = cg*4;
    #pragma unroll
    for (int r = 0; r < 16; r++){
      int row = row0 + rg*16 + r;
      float4 v; v.x=acc[r][0]; v.y=acc[r][1]; v.z=acc[r][2]; v.w=acc[r][3];
      if (c0 < 120){
        *(float4*)&xin[(size_t)row*120 + c0] = v;
      } else {
        v.x = siluf_(v.x); v.y = siluf_(v.y); v.z = siluf_(v.z); v.w = siluf_(v.w);
        *(float4*)&zs[(size_t)row*120 + (c0-120)] = v;
      }
    }
  }
}

// =============== fused conv1d + x_proj + dt_proj + softplus, 64-row tiled ===============
__global__ __launch_bounds__(256) void k_xprojc(
    const float* __restrict__ xin,
    const float* __restrict__ cw, const float* __restrict__ cb,
    const float* __restrict__ xpw,
    const float* __restrict__ dtw, const float* __restrict__ dtb,
    float* __restrict__ xc, float* __restrict__ delta, float* __restrict__ BC)
{
  __shared__ float XT[67*124];
  __shared__ float WxT[120*36];
  __shared__ float Wd5[120*5];
  __shared__ float cwL[120*4];
  __shared__ float bdL[120];
  __shared__ float cbL[120];
  __shared__ float dtsh[64*4];
  const int tid = threadIdx.x;
  const int row0 = blockIdx.x*64;
  const int seq0 = (row0 / LSEQ) * LSEQ;
  for (int i = tid; i < 36*120; i += 256){ int o=i/120, k=i%120; WxT[k*36+o] = xpw[i]; }
  for (int i = tid; i < 480; i += 256){ Wd5[(i/4)*5 + (i%4)] = dtw[i]; cwL[i] = cw[i]; }
  for (int i = tid; i < 120; i += 256){ bdL[i] = dtb[i]; cbL[i] = cb[i]; }
  for (int i = tid; i < 67*120; i += 256){
    int r = i/120, c = i%120;
    int grow = row0 - 3 + r;
    XT[r*124 + c] = (grow >= seq0) ? xin[(size_t)grow*120 + c] : 0.f;
  }
  __syncthreads();
  float xcv[30];
  #pragma unroll
  for (int j = 0; j < 30; j++){
    int i = tid + j*256;
    int r = i/120, c = i%120;
    float acc = cbL[c];
    #pragma unroll
    for (int k = 0; k < 4; k++) acc += cwL[c*4+k] * XT[(r+k)*124 + c];
    acc = siluf_(acc);
    xcv[j] = acc;
    xc[(size_t)(row0 + r)*120 + c] = acc;
  }
  __syncthreads();
  #pragma unroll
  for (int j = 0; j < 30; j++){
    int i = tid + j*256;
    int r = i/120, c = i%120;
    XT[r*124 + c] = xcv[j];
  }
  __syncthreads();
  if (tid < 144){
    const int cg = tid % 9, rg = tid / 9;
    float acc[4][4];
    #pragma unroll
    for (int r = 0; r < 4; r++){ acc[r][0]=0.f; acc[r][1]=0.f; acc[r][2]=0.f; acc[r][3]=0.f; }
    for (int kg = 0; kg < 30; kg++){
      int k = kg*4;
      float4 b0 = *(const float4*)&WxT[(k+0)*36 + cg*4];
      float4 b1 = *(const float4*)&WxT[(k+1)*36 + cg*4];
      float4 b2 = *(const float4*)&WxT[(k+2)*36 + cg*4];
      float4 b3 = *(const float4*)&WxT[(k+3)*36 + cg*4];
      #pragma unroll
      for (int r = 0; r < 4; r++){
        float4 a = *(const float4*)&XT[(rg*4+r)*124 + k];
        acc[r][0] += a.x*b0.x + a.y*b1.x + a.z*b2.x + a.w*b3.x;
        acc[r][1] += a.x*b0.y + a.y*b1.y + a.z*b2.y + a.w*b3.y;
        acc[r][2] += a.x*b0.z + a.y*b1.z + a.z*b2.z + a.w*b3.z;
        acc[r][3] += a.x*b0.w + a.y*b1.w + a.z*b2.w + a.w*b3.w;
      }
    }
    #pragma unroll
    for (int r = 0; r < 4; r++){
      int row = rg*4 + r;
      float4 v; v.x=acc[r][0]; v.y=acc[r][1]; v.z=acc[r][2]; v.w=acc[r][3];
      if (cg == 0) *(float4*)&dtsh[row*4] = v;
      else         *(float4*)&BC[((size_t)row0 + row)*32 + (cg*4 - 4)] = v;
    }
  }
  __syncthreads();
  #pragma unroll
  for (int j = 0; j < 30; j++){
    int i = tid + j*256;
    int row = i/120, d = i%120;
    float4 t = *(const float4*)&dtsh[row*4];
    float acc = bdL[d] + t.x*Wd5[d*5] + t.y*Wd5[d*5+1] + t.z*Wd5[d*5+2] + t.w*Wd5[d*5+3];
    delta[(size_t)(row0 + row)*120 + d] = softplusf_(acc);
  }
}

// =============== scan pass 1: per-chunk (prod dA, h_end | h0=0) ===============
__global__ __launch_bounds__(128) void k_scan1(
    const float* __restrict__ delta, const float* __restrict__ xc,
    const float* __restrict__ BC, const float* __restrict__ A_log,
    float* __restrict__ ap, float* __restrict__ he)
{
  __shared__ float Bl[TCH*16];
  const int tid = threadIdx.x;
  const int c = blockIdx.x % NCH, b = blockIdx.x / NCH;
  const size_t rowbase = (size_t)b*LSEQ + (size_t)c*TCH;
  for (int i = tid; i < TCH*16; i += 128){
    int t = i >> 4, n = i & 15;
    Bl[i] = BC[(rowbase + t)*32 + n];
  }
  __syncthreads();
  const int d = tid;
  if (d >= DI) return;
  float A2[16], h[16];
  #pragma unroll
  for (int n = 0; n < 16; n++){
    A2[n] = -__expf(A_log[d*16+n]) * 1.44269504f;
    h[n] = 0.f;
  }
  bool fastp = true;
  #pragma unroll
  for (int n = 1; n < 16; n++)
    fastp = fastp && (fabsf(A2[n] - (n+1)*A2[0]) <= 1e-4f*fabsf(A2[n]));
  int base = (c*BATCH + b)*(DI*16) + d*16;
  if (fastp){
    float P = 1.f;
    const float A20 = A2[0];
    for (int t = 0; t < TCH; t++){
      float del = delta[(rowbase+t)*DI + d];
      float xcv = xc[(rowbase+t)*DI + d];
      float dx = del * xcv;
      float r = exp2f(del * A20);
      P *= r;
      float dA[16]; powers16(r, dA);
      float4 b0 = *(const float4*)&Bl[t*16+0];
      float4 b1 = *(const float4*)&Bl[t*16+4];
      float4 b2 = *(const float4*)&Bl[t*16+8];
      float4 b3 = *(const float4*)&Bl[t*16+12];
      h[0]=dA[0]*h[0]+dx*b0.x;  h[1]=dA[1]*h[1]+dx*b0.y;  h[2]=dA[2]*h[2]+dx*b0.z;  h[3]=dA[3]*h[3]+dx*b0.w;
      h[4]=dA[4]*h[4]+dx*b1.x;  h[5]=dA[5]*h[5]+dx*b1.y;  h[6]=dA[6]*h[6]+dx*b1.z;  h[7]=dA[7]*h[7]+dx*b1.w;
      h[8]=dA[8]*h[8]+dx*b2.x;  h[9]=dA[9]*h[9]+dx*b2.y;  h[10]=dA[10]*h[10]+dx*b2.z; h[11]=dA[11]*h[11]+dx*b2.w;
      h[12]=dA[12]*h[12]+dx*b3.x; h[13]=dA[13]*h[13]+dx*b3.y; h[14]=dA[14]*h[14]+dx*b3.z; h[15]=dA[15]*h[15]+dx*b3.w;
    }
    float apv[16]; powers16(P, apv);
    #pragma unroll
    for (int n = 0; n < 16; n++){ ap[base+n] = apv[n]; he[base+n] = h[n]; }
  } else {
    float apv[16];
    #pragma unroll
    for (int n = 0; n < 16; n++) apv[n] = 1.f;
    for (int t = 0; t < TCH; t++){
      float del = delta[(rowbase+t)*DI + d];
      float xcv = xc[(rowbase+t)*DI + d];
      float dx = del * xcv;
      #pragma unroll
      for (int n = 0; n < 16; n++){
        float dA = exp2f(del * A2[n]);
        apv[n] *= dA;
        h[n] = dA*h[n] + dx*Bl[t*16+n];
      }
    }
    #pragma unroll
    for (int n = 0; n < 16; n++){ ap[base+n] = apv[n]; he[base+n] = h[n]; }
  }
}

// =============== scan pass 2: hierarchical block-parallel chunk scan ===============
// one block per (b,d); 256 thr = 16 segments (j) x 16 states (n); 32 chunks/segment
__global__ __launch_bounds__(256) void k_scan2(float* __restrict__ ap, const float* __restrict__ he)
{
  __shared__ float aggA[16*17];
  __shared__ float aggB[16*17];
  const int tid = threadIdx.x;
  const int n = tid & 15, j = tid >> 4;
  const int sbase = blockIdx.x*16 + n;      // blockIdx = b*120+d
  const int stride = BATCH*DI*16;           // 3840
  // Phase A: segment aggregate (A,B) with identity init
  {
    float A = 1.f, B = 0.f;
    int idx = (j*32)*stride + sbase;
    #pragma unroll 4
    for (int k = 0; k < 32; k++){
      float a = ap[idx], h = he[idx];
      B = a*B + h;
      A *= a;
      idx += stride;
    }
    aggA[n*17 + j] = A;
    aggB[n*17 + j] = B;
  }
  __syncthreads();
  // Phase B: exclusive prefix over 16 segments (serial per n)
  if (tid < 16){
    float A = 1.f, B = 0.f;
    #pragma unroll
    for (int jj = 0; jj < 16; jj++){
      float Af = aggA[tid*17 + jj];
      float Bf = aggB[tid*17 + jj];
      aggB[tid*17 + jj] = B;       // exclusive prefix B = state at segment start
      B = Af*B + Bf;
      A = A*Af;
    }
  }
  __syncthreads();
  // Phase C: replay segment from prefix state, write chunk-initial h0 over ap
  {
    float H = aggB[n*17 + j];
    int idx = (j*32)*stride + sbase;
    #pragma unroll 4
    for (int k = 0; k < 32; k++){
      float a = ap[idx], h = he[idx];
      ap[idx] = H;
      H = a*H + h;
      idx += stride;
    }
  }
}

// =============== scan pass 3 + out_proj fused ===============
__global__ __launch_bounds__(128) void k_scan3o(
    const float* __restrict__ delta, const float* __restrict__ xc,
    const float* __restrict__ BC, const float* __restrict__ zs,
    const float* __restrict__ h0, const float* __restrict__ A_log,
    const float* __restrict__ Dsk, const float* __restrict__ opw,
    float* __restrict__ hout)
{
  __shared__ float BCl[TCH*32];
  __shared__ float yL[TCH*124];
  const int tid = threadIdx.x;
  const int c = blockIdx.x % NCH, b = blockIdx.x / NCH;
  const size_t rowbase = (size_t)b*LSEQ + (size_t)c*TCH;
  for (int i = tid; i < TCH*32; i += 128)
    BCl[i] = BC[rowbase*32 + i];
  __syncthreads();
  const int d = tid;
  if (d < DI){
    float A2[16], h[16];
    int base = (c*BATCH + b)*(DI*16) + d*16;
    #pragma unroll
    for (int n = 0; n < 16; n++){
      A2[n] = -__expf(A_log[d*16+n]) * 1.44269504f;
      h[n] = h0[base+n];
    }
    bool fastp = true;
    #pragma unroll
    for (int n = 1; n < 16; n++)
      fastp = fastp && (fabsf(A2[n] - (n+1)*A2[0]) <= 1e-4f*fabsf(A2[n]));
    float Dv = Dsk[d];
    if (fastp){
      const float A20 = A2[0];
      for (int t = 0; t < TCH; t++){
        float del = delta[(rowbase+t)*DI + d];
        float xcv = xc[(rowbase+t)*DI + d];
        float zv  = zs[(rowbase+t)*DI + d];
        float dx = del * xcv;
        float r = exp2f(del * A20);
        float dA[16]; powers16(r, dA);
        float4 b0 = *(const float4*)&BCl[t*32+0];
        float4 b1 = *(const float4*)&BCl[t*32+4];
        float4 b2 = *(const float4*)&BCl[t*32+8];
        float4 b3 = *(const float4*)&BCl[t*32+12];
        float4 c0 = *(const float4*)&BCl[t*32+16];
        float4 c1 = *(const float4*)&BCl[t*32+20];
        float4 c2 = *(const float4*)&BCl[t*32+24];
        float4 c3 = *(const float4*)&BCl[t*32+28];
        h[0]=dA[0]*h[0]+dx*b0.x;  h[1]=dA[1]*h[1]+dx*b0.y;  h[2]=dA[2]*h[2]+dx*b0.z;  h[3]=dA[3]*h[3]+dx*b0.w;
        h[4]=dA[4]*h[4]+dx*b1.x;  h[5]=dA[5]*h[5]+dx*b1.y;  h[6]=dA[6]*h[6]+dx*b1.z;  h[7]=dA[7]*h[7]+dx*b1.w;
        h[8]=dA[8]*h[8]+dx*b2.x;  h[9]=dA[9]*h[9]+dx*b2.y;  h[10]=dA[10]*h[10]+dx*b2.z; h[11]=dA[11]*h[11]+dx*b2.w;
        h[12]=dA[12]*h[12]+dx*b3.x; h[13]=dA[13]*h[13]+dx*b3.y; h[14]=dA[14]*h[14]+dx*b3.z; h[15]=dA[15]*h[15]+dx*b3.w;
        float acc = h[0]*c0.x + h[1]*c0.y + h[2]*c0.z + h[3]*c0.w
                  + h[4]*c1.x + h[5]*c1.y + h[6]*c1.z + h[7]*c1.w
                  + h[8]*c2.x + h[9]*c2.y + h[10]*c2.z + h[11]*c2.w
                  + h[12]*c3.x + h[13]*c3.y + h[14]*c3.z + h[15]*c3.w;
        yL[t*124 + d] = (acc + Dv*xcv) * zv;
      }
    } else {
      for (int t = 0; t < TCH; t++){
        float del = delta[(rowbase+t)*DI + d];
        float xcv = xc[(rowbase+t)*DI + d];
        float zv  = zs[(rowbase+t)*DI + d];
        float dx = del * xcv;
        float acc = 0.f;
        #pragma unroll
        for (int n = 0; n < 16; n++){
          float dA = exp2f(del * A2[n]);
          h[n] = dA*h[n] + dx*BCl[t*32+n];
          acc += h[n]*BCl[t*32+16+n];
        }
        yL[t*124 + d] = (acc + Dv*xcv) * zv;
      }
    }
  }
  __syncthreads();
  if (tid < 120){
    const int cg = tid % 15, rg = tid / 15;
    float acc[4][4];
    #pragma unroll
    for (int r = 0; r < 4; r++){ acc[r][0]=0.f; acc[r][1]=0.f; acc[r][2]=0.f; acc[r][3]=0.f; }
    for (int kg = 0; kg < 30; kg++){
      int k = kg*4;
      float4 b0 = *(const float4*)&opw[(size_t)(cg*4+0)*120 + k];
      float4 b1 = *(const float4*)&opw[(size_t)(cg*4+1)*120 + k];
      float4 b2 = *(const float4*)&opw[(size_t)(cg*4+2)*120 + k];
      float4 b3 = *(const float4*)&opw[(size_t)(cg*4+3)*120 + k];
      #pragma unroll
      for (int r = 0; r < 4; r++){
        float4 a = *(const float4*)&yL[(rg*4+r)*124 + k];
        acc[r][0] += a.x*b0.x + a.y*b0.y + a.z*b0.z + a.w*b0.w;
        acc[r][1] += a.x*b1.x + a.y*b1.y + a.z*b1.z + a.w*b1.w;
        acc[r][2] += a.x*b2.x + a.y*b2.y + a.z*b2.z + a.w*b2.w;
        acc[r][3] += a.x*b3.x + a.y*b3.y + a.z*b3.z + a.w*b3.w;
      }
    }
    #pragma unroll
    for (int r = 0; r < 4; r++){
      float4 v; v.x=acc[r][0]; v.y=acc[r][1]; v.z=acc[r][2]; v.w=acc[r][3];
      *(float4*)&hout[(rowbase + rg*4 + r)*60 + cg*4] = v;
    }
  }
}

// =============== conv2d weight pack: w[co][ci][3][3] -> bf16 wB[tap][co64][ci64] ===============
__global__ __launch_bounds__(256) void k_wB(const float* __restrict__ w, short* __restrict__ wB)
{
  int i = blockIdx.x*256 + threadIdx.x;
  if (i >= 9*64*64) return;
  int ci = i & 63, co = (i >> 6) & 63, tap = i >> 12;
  float v = 0.f;
  if (co < 60 && ci < 60) v = w[((size_t)co*60 + ci)*9 + tap];
  wB[i] = f2b(v);
}

// =============== 3x3 SAME conv2d via bf16 MFMA + bias + residual ===============
__global__ __launch_bounds__(256) void k_conv2d(
    const float* __restrict__ hin, const short* __restrict__ wB,
    const float* __restrict__ cb, const float* __restrict__ xres,
    float* __restrict__ out)
{
  __shared__ short tile[3*66*72];
  const int tid = threadIdx.x;
  const int blk = blockIdx.x;
  const int xhalf = blk & 1;
  const int yy = (blk >> 1) & 127;
  const int b = blk >> 8;
  const int x0 = xhalf*64;
  for (int i = tid; i < 3*66*72; i += 256){
    int ci = i % 72;
    int xx = (i / 72) % 66;
    int row = i / (72*66);
    int gy = yy - 1 + row, gx = x0 - 1 + xx;
    float v = 0.f;
    if (ci < 60 && gy >= 0 && gy < HH && gx >= 0 && gx < WW)
      v = hin[((size_t)b*LSEQ + gy*WW + gx)*60 + ci];
    tile[i] = f2b(v);
  }
  __syncthreads();
  const int wave = tid >> 6, lane = tid & 63;
  const int m = lane & 15, quad = lane >> 4;
  f32x4 acc0 = {0.f,0.f,0.f,0.f}, acc1 = {0.f,0.f,0.f,0.f};
  f32x4 acc2 = {0.f,0.f,0.f,0.f}, acc3 = {0.f,0.f,0.f,0.f};
  #pragma unroll
  for (int tap = 0; tap < 9; tap++){
    const int ky = tap/3, kx = tap%3;
    const short* arow = &tile[(ky*66 + wave*16 + m + kx)*72];
    const short* brow = wB + tap*4096;
    #pragma unroll
    for (int kh = 0; kh < 2; kh++){
      const int k0 = kh*32 + quad*8;
      bhalf8 a = *(const bhalf8*)(arow + k0);
      bhalf8 b0 = *(const bhalf8*)(brow + (0*16 + m)*64 + k0);
      bhalf8 b1 = *(const bhalf8*)(brow + (1*16 + m)*64 + k0);
      bhalf8 b2 = *(const bhalf8*)(brow + (2*16 + m)*64 + k0);
      bhalf8 b3 = *(const bhalf8*)(brow + (3*16 + m)*64 + k0);
      acc0 = __builtin_amdgcn_mfma_f32_16x16x32_bf16(a, b0, acc0, 0, 0, 0);
      acc1 = __builtin_amdgcn_mfma_f32_16x16x32_bf16(a, b1, acc1, 0, 0, 0);
      acc2 = __builtin_amdgcn_mfma_f32_16x16x32_bf16(a, b2, acc2, 0, 0, 0);
      acc3 = __builtin_amdgcn_mfma_f32_16x16x32_bf16(a, b3, acc3, 0, 0, 0);
    }
  }
  const size_t rowb = (size_t)b*LSEQ + yy*WW + x0;
  f32x4 accs[4] = {acc0, acc1, acc2, acc3};
  #pragma unroll
  for (int nt = 0; nt < 4; nt++){
    int co = nt*16 + m;
    if (co < 60){
      float bias = cb[co];
      #pragma unroll
      for (int reg = 0; reg < 4; reg++){
        int px = wave*16 + quad*4 + reg;
        size_t o = (rowb + px)*60 + co;
        out[o] = accs[nt][reg] + bias + xres[o];
      }
    }
  }
}

extern "C" void kernel_launch(void* const* d_in, const int* in_sizes, int n_in,
                              void* d_out, int out_size, void* d_ws, size_t ws_size,
                              hipStream_t stream)
{
  const float* x      = (const float*)d_in[0];
  const float* ln_w   = (const float*)d_in[1];
  const float* ln_b   = (const float*)d_in[2];
  const float* ipw    = (const float*)d_in[3];
  const float* cw     = (const float*)d_in[4];
  const float* cb1    = (const float*)d_in[5];
  const float* xpw    = (const float*)d_in[6];
  const float* dtw    = (const float*)d_in[7];
  const float* dtb    = (const float*)d_in[8];
  const float* A_log  = (const float*)d_in[9];
  const float* Dsk    = (const float*)d_in[10];
  const float* opw    = (const float*)d_in[11];
  const float* c2w    = (const float*)d_in[12];
  const float* c2b    = (const float*)d_in[13];
  float* out = (float*)d_out;

  float* ws = (float*)d_ws;
  size_t off = 0;
  float* xin   = ws + off; off += (size_t)BATCH*LSEQ*DI;
  float* zsb   = ws + off; off += (size_t)BATCH*LSEQ*DI;
  float* xcb   = ws + off; off += (size_t)BATCH*LSEQ*DI;
  float* dlt   = ws + off; off += (size_t)BATCH*LSEQ*DI;
  float* BC    = ws + off; off += (size_t)BATCH*LSEQ*32;
  float* apb   = ws + off; off += (size_t)NCH*BATCH*DI*16;
  float* heb   = ws + off; off += (size_t)NCH*BATCH*DI*16;
  float* hcur  = ws + off; off += (size_t)BATCH*LSEQ*DM;
  short* wBb   = (short*)(ws + off); off += (size_t)9*64*64/2;

  const int rows = BATCH*LSEQ;
  for (int layer = 0; layer < 2; layer++){
    const float* src = (layer == 0) ? x : hcur;
    k_ln_inproj<<<rows/64, 256, 0, stream>>>(src, ln_w + layer*DM, ln_b + layer*DM,
                                             ipw + (size_t)layer*240*DM, xin, zsb);
    k_xprojc<<<rows/64, 256, 0, stream>>>(xin, cw + layer*DI*4, cb1 + layer*DI,
                                          xpw + (size_t)layer*36*DI, dtw + (size_t)layer*DI*4,
                                          dtb + layer*DI, xcb, dlt, BC);
    k_scan1<<<BATCH*NCH, 128, 0, stream>>>(dlt, xcb, BC, A_log + (size_t)layer*DI*16, apb, heb);
    k_scan2<<<BATCH*DI, 256, 0, stream>>>(apb, heb);
    k_scan3o<<<BATCH*NCH, 128, 0, stream>>>(dlt, xcb, BC, zsb, apb, A_log + (size_t)layer*DI*16,
                                            Dsk + layer*DI, opw + (size_t)layer*DM*DI, hcur);
  }
  k_wB<<<(9*64*64+255)/256, 256, 0, stream>>>(c2w, wBb);
  k_conv2d<<<BATCH*HH*2, 256, 0, stream>>>(hcur, wBb, c2b, x, out);
}

// Round 8
// 373.941 us; speedup vs baseline: 2.2803x; 1.1468x over previous
//
#include <hip/hip_runtime.h>
#include <math.h>

#define BATCH 2
#define LSEQ 16384
#define DM 60
#define DI 120
#define NCH 512
#define TCH 32    // LSEQ / NCH
#define HH 128
#define WW 128

typedef __attribute__((ext_vector_type(8))) short bhalf8;
typedef __attribute__((ext_vector_type(4))) float f32x4;

__device__ __forceinline__ float sigmoidf_(float x){ return 1.0f/(1.0f + __expf(-x)); }
__device__ __forceinline__ float siluf_(float x){ return x * sigmoidf_(x); }
__device__ __forceinline__ float softplusf_(float x){ return (x > 20.0f) ? x : log1pf(__expf(x)); }
__device__ __forceinline__ short f2b(float f){   // RNE fp32->bf16 (finite inputs)
  union{float f; unsigned u;} v; v.f = f;
  unsigned r = (v.u + 0x7fffu + ((v.u >> 16) & 1u)) >> 16;
  return (short)r;
}
__device__ __forceinline__ float b2f(short s){
  union{float f; unsigned u;} v; v.u = ((unsigned)(unsigned short)s) << 16; return v.f;
}

__device__ __forceinline__ float waveReduceSum(float v){
  #pragma unroll
  for (int off = 32; off > 0; off >>= 1) v += __shfl_xor(v, off, 64);
  return v;
}

// powers: dA[n] = r^(n+1), log-depth tree
__device__ __forceinline__ void powers16(float r, float* dA){
  dA[0] = r;
  #pragma unroll
  for (int n = 1; n < 16; n++) dA[n] = dA[(n-1)>>1] * dA[n>>1];
}

// =============== weight pre-pack: ipw -> ipB bf16 [l][240][64]; xpw -> xpB bf16 [l][48][128] ===============
__global__ __launch_bounds__(256) void k_pack(
    const float* __restrict__ ipw, const float* __restrict__ xpw, short* __restrict__ pk)
{
  int i = blockIdx.x*256 + threadIdx.x;
  if (i < 2*240*64){
    int l = i / (240*64);
    int rem = i % (240*64);
    int n = rem / 64, k = rem % 64;
    float v = (k < 60) ? ipw[(size_t)l*240*60 + n*60 + k] : 0.f;
    pk[i] = f2b(v);
  } else if (i < 30720 + 2*48*128){
    int j = i - 30720;
    int l = j / (48*128);
    int rem = j % (48*128);
    int n = rem / 128, k = rem % 128;
    float v = (n < 36 && k < 120) ? xpw[(size_t)l*36*120 + n*120 + k] : 0.f;
    pk[i] = f2b(v);
  }
}

// =============== fused LN + in_proj(MFMA) + conv1d + x_proj(MFMA) + dt_proj ===============
// 64 output rows per block; halo of 3 for causal conv1d.
__global__ __launch_bounds__(256) void k_lnxp(
    const float* __restrict__ src,
    const float* __restrict__ ln_w, const float* __restrict__ ln_b,
    const short* __restrict__ ipB,   // [240][64] bf16, layer base
    const float* __restrict__ cw, const float* __restrict__ cb,
    const short* __restrict__ xpB,   // [48][128] bf16, layer base
    const float* __restrict__ dtw, const float* __restrict__ dtb,
    float* __restrict__ zs, float* __restrict__ xc,
    float* __restrict__ delta, float* __restrict__ BC)
{
  __shared__ __align__(16) char smem[45472];
  short* hnB  = (short*)smem;            // [80][72] bf16 (phase 1-2)
  short* xcB  = (short*)smem;            // [64][136] bf16 (phase 3+, aliases hnB)
  short* xinB = (short*)(smem + 17408);  // [80][136] bf16
  float* dtsh = (float*)(smem + 39168);  // [64][4]
  float* cwL  = (float*)(smem + 40192);  // [120][4]
  float* cbL  = (float*)(smem + 42112);  // [120]
  float* Wd5  = (float*)(smem + 42592);  // [120][5]
  float* bdL  = (float*)(smem + 44992);  // [120]
  const int tid = threadIdx.x;
  const int wave = tid >> 6, lane = tid & 63;
  const int m = lane & 15, quad = lane >> 4;
  const int row0 = blockIdx.x * 64;
  const int seq0 = (row0 / LSEQ) * LSEQ;
  for (int i = tid; i < 480; i += 256){ cwL[i] = cw[i]; Wd5[(i/4)*5 + (i%4)] = dtw[i]; }
  for (int i = tid; i < 120; i += 256){ cbL[i] = cb[i]; bdL[i] = dtb[i]; }
  // phase 1: LN -> hnB bf16 (rows 0..79; r>=67 or pre-batch -> 0)
  float lw = (lane < 60) ? ln_w[lane] : 0.f;
  float lb = (lane < 60) ? ln_b[lane] : 0.f;
  for (int r = wave; r < 80; r += 4){
    int grow = row0 - 3 + r;
    bool valid = (r < 67) && (grow >= seq0);
    float v = (valid && lane < 60) ? src[(size_t)grow*60 + lane] : 0.f;
    float mu = waveReduceSum(v) * (1.0f/60.0f);
    float dv = (valid && lane < 60) ? (v - mu) : 0.f;
    float var = waveReduceSum(dv*dv) * (1.0f/60.0f);
    float rs = rsqrtf(var + 1e-5f);
    float hv = (valid && lane < 60) ? (dv*rs*lw + lb) : 0.f;
    hnB[r*72 + lane] = f2b(hv);
  }
  __syncthreads();
  // phase 2: in_proj MFMA, 5 mtiles x 15 ntiles; D: row=quad*4+reg, col=m
  for (int t = wave; t < 75; t += 4){
    int mtile = t / 15, ntile = t % 15;
    f32x4 acc = {0.f,0.f,0.f,0.f};
    #pragma unroll
    for (int ks = 0; ks < 2; ks++){
      bhalf8 a = *(const bhalf8*)&hnB[(mtile*16 + m)*72 + ks*32 + quad*8];
      bhalf8 b = *(const bhalf8*)&ipB[(ntile*16 + m)*64 + ks*32 + quad*8];
      acc = __builtin_amdgcn_mfma_f32_16x16x32_bf16(a, b, acc, 0, 0, 0);
    }
    int n = ntile*16 + m;
    #pragma unroll
    for (int reg = 0; reg < 4; reg++){
      int r = mtile*16 + quad*4 + reg;
      float val = acc[reg];
      if (n < 120){
        xinB[r*136 + n] = f2b(val);
      } else if (r >= 3 && r < 67){
        zs[(size_t)(row0 - 3 + r)*120 + (n - 120)] = siluf_(val);
      }
    }
  }
  __syncthreads();
  // phase 3: conv1d(4 taps)+silu -> xc global fp32 + xcB bf16 (K-pad 120..127 = 0)
  #pragma unroll
  for (int j = 0; j < 30; j++){
    int i = tid + j*256;
    int r = i/120, c = i%120;
    float a = cbL[c];
    #pragma unroll
    for (int k = 0; k < 4; k++)
      a += cwL[c*4+k] * b2f(xinB[(r+k)*136 + c]);
    a = siluf_(a);
    xc[(size_t)(row0 + r)*120 + c] = a;
    xcB[r*136 + c] = f2b(a);
  }
  for (int i = tid; i < 64*8; i += 256)
    xcB[(i >> 3)*136 + 120 + (i & 7)] = 0;
  __syncthreads();
  // phase 4: x_proj MFMA: wave w -> mtile w; 3 ntiles; K=128
  {
    f32x4 acc0 = {0.f,0.f,0.f,0.f}, acc1 = {0.f,0.f,0.f,0.f}, acc2 = {0.f,0.f,0.f,0.f};
    #pragma unroll
    for (int ks = 0; ks < 4; ks++){
      bhalf8 a  = *(const bhalf8*)&xcB[(wave*16 + m)*136 + ks*32 + quad*8];
      bhalf8 b0 = *(const bhalf8*)&xpB[(0*16 + m)*128 + ks*32 + quad*8];
      bhalf8 b1 = *(const bhalf8*)&xpB[(1*16 + m)*128 + ks*32 + quad*8];
      bhalf8 b2 = *(const bhalf8*)&xpB[(2*16 + m)*128 + ks*32 + quad*8];
      acc0 = __builtin_amdgcn_mfma_f32_16x16x32_bf16(a, b0, acc0, 0, 0, 0);
      acc1 = __builtin_amdgcn_mfma_f32_16x16x32_bf16(a, b1, acc1, 0, 0, 0);
      acc2 = __builtin_amdgcn_mfma_f32_16x16x32_bf16(a, b2, acc2, 0, 0, 0);
    }
    f32x4 accs[3] = {acc0, acc1, acc2};
    #pragma unroll
    for (int nt = 0; nt < 3; nt++){
      int n = nt*16 + m;
      #pragma unroll
      for (int reg = 0; reg < 4; reg++){
        int r = wave*16 + quad*4 + reg;
        float val = accs[nt][reg];
        if (n < 4)       dtsh[r*4 + n] = val;
        else if (n < 36) BC[(size_t)(row0 + r)*32 + (n - 4)] = val;
      }
    }
  }
  __syncthreads();
  // phase 5: dt_proj + softplus
  #pragma unroll
  for (int j = 0; j < 30; j++){
    int i = tid + j*256;
    int row = i/120, d = i%120;
    float t0 = dtsh[row*4], t1 = dtsh[row*4+1], t2 = dtsh[row*4+2], t3 = dtsh[row*4+3];
    float a = bdL[d] + t0*Wd5[d*5] + t1*Wd5[d*5+1] + t2*Wd5[d*5+2] + t3*Wd5[d*5+3];
    delta[(size_t)(row0 + row)*120 + d] = softplusf_(a);
  }
}

// =============== scan pass 1: per-chunk (prod dA, h_end | h0=0) ===============
__global__ __launch_bounds__(128) void k_scan1(
    const float* __restrict__ delta, const float* __restrict__ xc,
    const float* __restrict__ BC, const float* __restrict__ A_log,
    float* __restrict__ ap, float* __restrict__ he)
{
  __shared__ float Bl[TCH*16];
  const int tid = threadIdx.x;
  const int c = blockIdx.x % NCH, b = blockIdx.x / NCH;
  const size_t rowbase = (size_t)b*LSEQ + (size_t)c*TCH;
  for (int i = tid; i < TCH*16; i += 128){
    int t = i >> 4, n = i & 15;
    Bl[i] = BC[(rowbase + t)*32 + n];
  }
  __syncthreads();
  const int d = tid;
  if (d >= DI) return;
  float A2[16], h[16];
  #pragma unroll
  for (int n = 0; n < 16; n++){
    A2[n] = -__expf(A_log[d*16+n]) * 1.44269504f;
    h[n] = 0.f;
  }
  bool fastp = true;
  #pragma unroll
  for (int n = 1; n < 16; n++)
    fastp = fastp && (fabsf(A2[n] - (n+1)*A2[0]) <= 1e-4f*fabsf(A2[n]));
  int base = (c*BATCH + b)*(DI*16) + d*16;
  if (fastp){
    float P = 1.f;
    const float A20 = A2[0];
    for (int t = 0; t < TCH; t++){
      float del = delta[(rowbase+t)*DI + d];
      float xcv = xc[(rowbase+t)*DI + d];
      float dx = del * xcv;
      float r = exp2f(del * A20);
      P *= r;
      float dA[16]; powers16(r, dA);
      float4 b0 = *(const float4*)&Bl[t*16+0];
      float4 b1 = *(const float4*)&Bl[t*16+4];
      float4 b2 = *(const float4*)&Bl[t*16+8];
      float4 b3 = *(const float4*)&Bl[t*16+12];
      h[0]=dA[0]*h[0]+dx*b0.x;  h[1]=dA[1]*h[1]+dx*b0.y;  h[2]=dA[2]*h[2]+dx*b0.z;  h[3]=dA[3]*h[3]+dx*b0.w;
      h[4]=dA[4]*h[4]+dx*b1.x;  h[5]=dA[5]*h[5]+dx*b1.y;  h[6]=dA[6]*h[6]+dx*b1.z;  h[7]=dA[7]*h[7]+dx*b1.w;
      h[8]=dA[8]*h[8]+dx*b2.x;  h[9]=dA[9]*h[9]+dx*b2.y;  h[10]=dA[10]*h[10]+dx*b2.z; h[11]=dA[11]*h[11]+dx*b2.w;
      h[12]=dA[12]*h[12]+dx*b3.x; h[13]=dA[13]*h[13]+dx*b3.y; h[14]=dA[14]*h[14]+dx*b3.z; h[15]=dA[15]*h[15]+dx*b3.w;
    }
    float apv[16]; powers16(P, apv);
    #pragma unroll
    for (int n = 0; n < 16; n++){ ap[base+n] = apv[n]; he[base+n] = h[n]; }
  } else {
    float apv[16];
    #pragma unroll
    for (int n = 0; n < 16; n++) apv[n] = 1.f;
    for (int t = 0; t < TCH; t++){
      float del = delta[(rowbase+t)*DI + d];
      float xcv = xc[(rowbase+t)*DI + d];
      float dx = del * xcv;
      #pragma unroll
      for (int n = 0; n < 16; n++){
        float dA = exp2f(del * A2[n]);
        apv[n] *= dA;
        h[n] = dA*h[n] + dx*Bl[t*16+n];
      }
    }
    #pragma unroll
    for (int n = 0; n < 16; n++){ ap[base+n] = apv[n]; he[base+n] = h[n]; }
  }
}

// =============== scan pass 2: hierarchical block-parallel chunk scan ===============
__global__ __launch_bounds__(256) void k_scan2(float* __restrict__ ap, const float* __restrict__ he)
{
  __shared__ float aggA[16*17];
  __shared__ float aggB[16*17];
  const int tid = threadIdx.x;
  const int n = tid & 15, j = tid >> 4;
  const int sbase = blockIdx.x*16 + n;
  const int stride = BATCH*DI*16;
  {
    float A = 1.f, B = 0.f;
    int idx = (j*32)*stride + sbase;
    #pragma unroll 4
    for (int k = 0; k < 32; k++){
      float a = ap[idx], h = he[idx];
      B = a*B + h;
      A *= a;
      idx += stride;
    }
    aggA[n*17 + j] = A;
    aggB[n*17 + j] = B;
  }
  __syncthreads();
  if (tid < 16){
    float B = 0.f;
    #pragma unroll
    for (int jj = 0; jj < 16; jj++){
      float Af = aggA[tid*17 + jj];
      float Bf = aggB[tid*17 + jj];
      aggB[tid*17 + jj] = B;
      B = Af*B + Bf;
    }
  }
  __syncthreads();
  {
    float H = aggB[n*17 + j];
    int idx = (j*32)*stride + sbase;
    #pragma unroll 4
    for (int k = 0; k < 32; k++){
      float a = ap[idx], h = he[idx];
      ap[idx] = H;
      H = a*H + h;
      idx += stride;
    }
  }
}

// =============== scan pass 3 + out_proj fused ===============
__global__ __launch_bounds__(128) void k_scan3o(
    const float* __restrict__ delta, const float* __restrict__ xc,
    const float* __restrict__ BC, const float* __restrict__ zs,
    const float* __restrict__ h0, const float* __restrict__ A_log,
    const float* __restrict__ Dsk, const float* __restrict__ opw,
    float* __restrict__ hout)
{
  __shared__ float BCl[TCH*32];
  __shared__ float yL[TCH*124];
  const int tid = threadIdx.x;
  const int c = blockIdx.x % NCH, b = blockIdx.x / NCH;
  const size_t rowbase = (size_t)b*LSEQ + (size_t)c*TCH;
  for (int i = tid; i < TCH*32; i += 128)
    BCl[i] = BC[rowbase*32 + i];
  __syncthreads();
  const int d = tid;
  if (d < DI){
    float A2[16], h[16];
    int base = (c*BATCH + b)*(DI*16) + d*16;
    #pragma unroll
    for (int n = 0; n < 16; n++){
      A2[n] = -__expf(A_log[d*16+n]) * 1.44269504f;
      h[n] = h0[base+n];
    }
    bool fastp = true;
    #pragma unroll
    for (int n = 1; n < 16; n++)
      fastp = fastp && (fabsf(A2[n] - (n+1)*A2[0]) <= 1e-4f*fabsf(A2[n]));
    float Dv = Dsk[d];
    if (fastp){
      const float A20 = A2[0];
      for (int t = 0; t < TCH; t++){
        float del = delta[(rowbase+t)*DI + d];
        float xcv = xc[(rowbase+t)*DI + d];
        float zv  = zs[(rowbase+t)*DI + d];
        float dx = del * xcv;
        float r = exp2f(del * A20);
        float dA[16]; powers16(r, dA);
        float4 b0 = *(const float4*)&BCl[t*32+0];
        float4 b1 = *(const float4*)&BCl[t*32+4];
        float4 b2 = *(const float4*)&BCl[t*32+8];
        float4 b3 = *(const float4*)&BCl[t*32+12];
        float4 c0 = *(const float4*)&BCl[t*32+16];
        float4 c1 = *(const float4*)&BCl[t*32+20];
        float4 c2 = *(const float4*)&BCl[t*32+24];
        float4 c3 = *(const float4*)&BCl[t*32+28];
        h[0]=dA[0]*h[0]+dx*b0.x;  h[1]=dA[1]*h[1]+dx*b0.y;  h[2]=dA[2]*h[2]+dx*b0.z;  h[3]=dA[3]*h[3]+dx*b0.w;
        h[4]=dA[4]*h[4]+dx*b1.x;  h[5]=dA[5]*h[5]+dx*b1.y;  h[6]=dA[6]*h[6]+dx*b1.z;  h[7]=dA[7]*h[7]+dx*b1.w;
        h[8]=dA[8]*h[8]+dx*b2.x;  h[9]=dA[9]*h[9]+dx*b2.y;  h[10]=dA[10]*h[10]+dx*b2.z; h[11]=dA[11]*h[11]+dx*b2.w;
        h[12]=dA[12]*h[12]+dx*b3.x; h[13]=dA[13]*h[13]+dx*b3.y; h[14]=dA[14]*h[14]+dx*b3.z; h[15]=dA[15]*h[15]+dx*b3.w;
        float acc = h[0]*c0.x + h[1]*c0.y + h[2]*c0.z + h[3]*c0.w
                  + h[4]*c1.x + h[5]*c1.y + h[6]*c1.z + h[7]*c1.w
                  + h[8]*c2.x + h[9]*c2.y + h[10]*c2.z + h[11]*c2.w
                  + h[12]*c3.x + h[13]*c3.y + h[14]*c3.z + h[15]*c3.w;
        yL[t*124 + d] = (acc + Dv*xcv) * zv;
      }
    } else {
      for (int t = 0; t < TCH; t++){
        float del = delta[(rowbase+t)*DI + d];
        float xcv = xc[(rowbase+t)*DI + d];
        float zv  = zs[(rowbase+t)*DI + d];
        float dx = del * xcv;
        float acc = 0.f;
        #pragma unroll
        for (int n = 0; n < 16; n++){
          float dA = exp2f(del * A2[n]);
          h[n] = dA*h[n] + dx*BCl[t*32+n];
          acc += h[n]*BCl[t*32+16+n];
        }
        yL[t*124 + d] = (acc + Dv*xcv) * zv;
      }
    }
  }
  __syncthreads();
  if (tid < 120){
    const int cg = tid % 15, rg = tid / 15;
    float acc[4][4];
    #pragma unroll
    for (int r = 0; r < 4; r++){ acc[r][0]=0.f; acc[r][1]=0.f; acc[r][2]=0.f; acc[r][3]=0.f; }
    for (int kg = 0; kg < 30; kg++){
      int k = kg*4;
      float4 b0 = *(const float4*)&opw[(size_t)(cg*4+0)*120 + k];
      float4 b1 = *(const float4*)&opw[(size_t)(cg*4+1)*120 + k];
      float4 b2 = *(const float4*)&opw[(size_t)(cg*4+2)*120 + k];
      float4 b3 = *(const float4*)&opw[(size_t)(cg*4+3)*120 + k];
      #pragma unroll
      for (int r = 0; r < 4; r++){
        float4 a = *(const float4*)&yL[(rg*4+r)*124 + k];
        acc[r][0] += a.x*b0.x + a.y*b0.y + a.z*b0.z + a.w*b0.w;
        acc[r][1] += a.x*b1.x + a.y*b1.y + a.z*b1.z + a.w*b1.w;
        acc[r][2] += a.x*b2.x + a.y*b2.y + a.z*b2.z + a.w*b2.w;
        acc[r][3] += a.x*b3.x + a.y*b3.y + a.z*b3.z + a.w*b3.w;
      }
    }
    #pragma unroll
    for (int r = 0; r < 4; r++){
      float4 v; v.x=acc[r][0]; v.y=acc[r][1]; v.z=acc[r][2]; v.w=acc[r][3];
      *(float4*)&hout[(rowbase + rg*4 + r)*60 + cg*4] = v;
    }
  }
}

// =============== conv2d weight pack: w[co][ci][3][3] -> bf16 wB[tap][co64][ci64] ===============
__global__ __launch_bounds__(256) void k_wB(const float* __restrict__ w, short* __restrict__ wB)
{
  int i = blockIdx.x*256 + threadIdx.x;
  if (i >= 9*64*64) return;
  int ci = i & 63, co = (i >> 6) & 63, tap = i >> 12;
  float v = 0.f;
  if (co < 60 && ci < 60) v = w[((size_t)co*60 + ci)*9 + tap];
  wB[i] = f2b(v);
}

// =============== 3x3 SAME conv2d via bf16 MFMA + bias + residual ===============
__global__ __launch_bounds__(256) void k_conv2d(
    const float* __restrict__ hin, const short* __restrict__ wB,
    const float* __restrict__ cb, const float* __restrict__ xres,
    float* __restrict__ out)
{
  __shared__ short tile[3*66*72];
  const int tid = threadIdx.x;
  const int blk = blockIdx.x;
  const int xhalf = blk & 1;
  const int yy = (blk >> 1) & 127;
  const int b = blk >> 8;
  const int x0 = xhalf*64;
  for (int i = tid; i < 3*66*72; i += 256){
    int ci = i % 72;
    int xx = (i / 72) % 66;
    int row = i / (72*66);
    int gy = yy - 1 + row, gx = x0 - 1 + xx;
    float v = 0.f;
    if (ci < 60 && gy >= 0 && gy < HH && gx >= 0 && gx < WW)
      v = hin[((size_t)b*LSEQ + gy*WW + gx)*60 + ci];
    tile[i] = f2b(v);
  }
  __syncthreads();
  const int wave = tid >> 6, lane = tid & 63;
  const int m = lane & 15, quad = lane >> 4;
  f32x4 acc0 = {0.f,0.f,0.f,0.f}, acc1 = {0.f,0.f,0.f,0.f};
  f32x4 acc2 = {0.f,0.f,0.f,0.f}, acc3 = {0.f,0.f,0.f,0.f};
  #pragma unroll
  for (int tap = 0; tap < 9; tap++){
    const int ky = tap/3, kx = tap%3;
    const short* arow = &tile[(ky*66 + wave*16 + m + kx)*72];
    const short* brow = wB + tap*4096;
    #pragma unroll
    for (int kh = 0; kh < 2; kh++){
      const int k0 = kh*32 + quad*8;
      bhalf8 a = *(const bhalf8*)(arow + k0);
      bhalf8 b0 = *(const bhalf8*)(brow + (0*16 + m)*64 + k0);
      bhalf8 b1 = *(const bhalf8*)(brow + (1*16 + m)*64 + k0);
      bhalf8 b2 = *(const bhalf8*)(brow + (2*16 + m)*64 + k0);
      bhalf8 b3 = *(const bhalf8*)(brow + (3*16 + m)*64 + k0);
      acc0 = __builtin_amdgcn_mfma_f32_16x16x32_bf16(a, b0, acc0, 0, 0, 0);
      acc1 = __builtin_amdgcn_mfma_f32_16x16x32_bf16(a, b1, acc1, 0, 0, 0);
      acc2 = __builtin_amdgcn_mfma_f32_16x16x32_bf16(a, b2, acc2, 0, 0, 0);
      acc3 = __builtin_amdgcn_mfma_f32_16x16x32_bf16(a, b3, acc3, 0, 0, 0);
    }
  }
  const size_t rowb = (size_t)b*LSEQ + yy*WW + x0;
  f32x4 accs[4] = {acc0, acc1, acc2, acc3};
  #pragma unroll
  for (int nt = 0; nt < 4; nt++){
    int co = nt*16 + m;
    if (co < 60){
      float bias = cb[co];
      #pragma unroll
      for (int reg = 0; reg < 4; reg++){
        int px = wave*16 + quad*4 + reg;
        size_t o = (rowb + px)*60 + co;
        out[o] = accs[nt][reg] + bias + xres[o];
      }
    }
  }
}

extern "C" void kernel_launch(void* const* d_in, const int* in_sizes, int n_in,
                              void* d_out, int out_size, void* d_ws, size_t ws_size,
                              hipStream_t stream)
{
  const float* x      = (const float*)d_in[0];
  const float* ln_w   = (const float*)d_in[1];
  const float* ln_b   = (const float*)d_in[2];
  const float* ipw    = (const float*)d_in[3];
  const float* cw     = (const float*)d_in[4];
  const float* cb1    = (const float*)d_in[5];
  const float* xpw    = (const float*)d_in[6];
  const float* dtw    = (const float*)d_in[7];
  const float* dtb    = (const float*)d_in[8];
  const float* A_log  = (const float*)d_in[9];
  const float* Dsk    = (const float*)d_in[10];
  const float* opw    = (const float*)d_in[11];
  const float* c2w    = (const float*)d_in[12];
  const float* c2b    = (const float*)d_in[13];
  float* out = (float*)d_out;

  float* ws = (float*)d_ws;
  size_t off = 0;
  float* zsb   = ws + off; off += (size_t)BATCH*LSEQ*DI;
  float* xcb   = ws + off; off += (size_t)BATCH*LSEQ*DI;
  float* dlt   = ws + off; off += (size_t)BATCH*LSEQ*DI;
  float* BC    = ws + off; off += (size_t)BATCH*LSEQ*32;
  float* apb   = ws + off; off += (size_t)NCH*BATCH*DI*16;
  float* heb   = ws + off; off += (size_t)NCH*BATCH*DI*16;
  float* hcur  = ws + off; off += (size_t)BATCH*LSEQ*DM;
  short* wBb   = (short*)(ws + off); off += (size_t)9*64*64/2;
  short* pkb   = (short*)(ws + off); off += (size_t)(2*240*64 + 2*48*128)/2;

  const int rows = BATCH*LSEQ;
  k_pack<<<(2*240*64 + 2*48*128 + 255)/256, 256, 0, stream>>>(ipw, xpw, pkb);
  for (int layer = 0; layer < 2; layer++){
    const float* src = (layer == 0) ? x : hcur;
    k_lnxp<<<rows/64, 256, 0, stream>>>(src, ln_w + layer*DM, ln_b + layer*DM,
                                        pkb + (size_t)layer*240*64,
                                        cw + layer*DI*4, cb1 + layer*DI,
                                        pkb + 30720 + (size_t)layer*48*128,
                                        dtw + (size_t)layer*DI*4, dtb + layer*DI,
                                        zsb, xcb, dlt, BC);
    k_scan1<<<BATCH*NCH, 128, 0, stream>>>(dlt, xcb, BC, A_log + (size_t)layer*DI*16, apb, heb);
    k_scan2<<<BATCH*DI, 256, 0, stream>>>(apb, heb);
    k_scan3o<<<BATCH*NCH, 128, 0, stream>>>(dlt, xcb, BC, zsb, apb, A_log + (size_t)layer*DI*16,
                                            Dsk + layer*DI, opw + (size_t)layer*DM*DI, hcur);
  }
  k_wB<<<(9*64*64+255)/256, 256, 0, stream>>>(c2w, wBb);
  k_conv2d<<<BATCH*HH*2, 256, 0, stream>>>(hcur, wBb, c2b, x, out);
}

// Round 9
// 339.547 us; speedup vs baseline: 2.5113x; 1.1013x over previous
//
#include <hip/hip_runtime.h>
#include <math.h>

#define BATCH 2
#define LSEQ 16384
#define DM 60
#define DI 120
#define NCH 512
#define TCH 32    // LSEQ / NCH
#define HH 128
#define WW 128

typedef __attribute__((ext_vector_type(8))) short bhalf8;
typedef __attribute__((ext_vector_type(4))) float f32x4;

__device__ __forceinline__ float sigmoidf_(float x){ return __builtin_amdgcn_rcpf(1.0f + __expf(-x)); }
__device__ __forceinline__ float siluf_(float x){ return x * sigmoidf_(x); }
__device__ __forceinline__ float softplusf_(float x){ return (x > 20.0f) ? x : __logf(1.0f + __expf(x)); }
__device__ __forceinline__ short f2b(float f){   // RNE fp32->bf16 (finite inputs)
  union{float f; unsigned u;} v; v.f = f;
  unsigned r = (v.u + 0x7fffu + ((v.u >> 16) & 1u)) >> 16;
  return (short)r;
}
__device__ __forceinline__ float b2f(short s){
  union{float f; unsigned u;} v; v.u = ((unsigned)(unsigned short)s) << 16; return v.f;
}

__device__ __forceinline__ float waveReduceSum(float v){
  #pragma unroll
  for (int off = 32; off > 0; off >>= 1) v += __shfl_xor(v, off, 64);
  return v;
}

// powers: dA[n] = r^(n+1), log-depth tree
__device__ __forceinline__ void powers16(float r, float* dA){
  dA[0] = r;
  #pragma unroll
  for (int n = 1; n < 16; n++) dA[n] = dA[(n-1)>>1] * dA[n>>1];
}

// =============== weight pre-pack: ipw -> [l][240][64] bf16; xpw -> [l][48][128] bf16 ===============
__global__ __launch_bounds__(256) void k_pack(
    const float* __restrict__ ipw, const float* __restrict__ xpw, short* __restrict__ pk)
{
  int i = blockIdx.x*256 + threadIdx.x;
  if (i < 2*240*64){
    int l = i / (240*64);
    int rem = i % (240*64);
    int n = rem / 64, k = rem % 64;
    float v = (k < 60) ? ipw[(size_t)l*240*60 + n*60 + k] : 0.f;
    pk[i] = f2b(v);
  } else if (i < 30720 + 2*48*128){
    int j = i - 30720;
    int l = j / (48*128);
    int rem = j % (48*128);
    int n = rem / 128, k = rem % 128;
    float v = (n < 36 && k < 120) ? xpw[(size_t)l*36*120 + n*120 + k] : 0.f;
    pk[i] = f2b(v);
  }
}

// ====== fused LN + in_proj(MFMA) + conv1d + x_proj(MFMA) + dt_proj + chunk-scan (scan1) ======
// 64 output rows (2 scan chunks) per block; halo 3 for causal conv1d.
__global__ __launch_bounds__(256) void k_lnxp(
    const float* __restrict__ src,
    const float* __restrict__ ln_w, const float* __restrict__ ln_b,
    const short* __restrict__ ipB,   // [240][64] bf16
    const float* __restrict__ cw, const float* __restrict__ cb,
    const short* __restrict__ xpB,   // [48][128] bf16
    const float* __restrict__ dtw, const float* __restrict__ dtb,
    const float* __restrict__ A_log,
    short* __restrict__ zs, short* __restrict__ xcg,
    short* __restrict__ delta, float* __restrict__ BC,
    float* __restrict__ ap, float* __restrict__ he)
{
  __shared__ __align__(16) char smem[49568];
  short* hnB  = (short*)smem;            // [80][72] bf16 (phase 1-2)
  short* xcB  = (short*)smem;            // [64][136] bf16 (phase 3+, aliases hnB)
  short* xinB = (short*)(smem + 17408);  // [80][136] bf16
  float* dtsh = (float*)(smem + 39168);  // [64][4]
  float* BL   = (float*)(smem + 40192);  // [64][16] fp32 B
  float* cwL  = (float*)(smem + 44288);  // [120][4]
  float* cbL  = (float*)(smem + 46208);  // [120]
  float* Wd5  = (float*)(smem + 46688);  // [120][5]
  float* bdL  = (float*)(smem + 49088);  // [120]
  const int tid = threadIdx.x;
  const int wave = tid >> 6, lane = tid & 63;
  const int m = lane & 15, quad = lane >> 4;
  const int row0 = blockIdx.x * 64;
  const int seq0 = (row0 / LSEQ) * LSEQ;
  for (int i = tid; i < 480; i += 256){ cwL[i] = cw[i]; Wd5[(i/4)*5 + (i%4)] = dtw[i]; }
  for (int i = tid; i < 120; i += 256){ cbL[i] = cb[i]; bdL[i] = dtb[i]; }
  // phase 1: LN -> hnB bf16 (rows 0..79; r>=67 or pre-batch -> 0)
  float lw = (lane < 60) ? ln_w[lane] : 0.f;
  float lb = (lane < 60) ? ln_b[lane] : 0.f;
  for (int r = wave; r < 80; r += 4){
    int grow = row0 - 3 + r;
    bool valid = (r < 67) && (grow >= seq0);
    float v = (valid && lane < 60) ? src[(size_t)grow*60 + lane] : 0.f;
    float mu = waveReduceSum(v) * (1.0f/60.0f);
    float dv = (valid && lane < 60) ? (v - mu) : 0.f;
    float var = waveReduceSum(dv*dv) * (1.0f/60.0f);
    float rs = rsqrtf(var + 1e-5f);
    float hv = (valid && lane < 60) ? (dv*rs*lw + lb) : 0.f;
    hnB[r*72 + lane] = f2b(hv);
  }
  __syncthreads();
  // phase 2: in_proj MFMA, 5 mtiles x 15 ntiles
  for (int t = wave; t < 75; t += 4){
    int mtile = t / 15, ntile = t % 15;
    f32x4 acc = {0.f,0.f,0.f,0.f};
    #pragma unroll
    for (int ks = 0; ks < 2; ks++){
      bhalf8 a = *(const bhalf8*)&hnB[(mtile*16 + m)*72 + ks*32 + quad*8];
      bhalf8 b = *(const bhalf8*)&ipB[(ntile*16 + m)*64 + ks*32 + quad*8];
      acc = __builtin_amdgcn_mfma_f32_16x16x32_bf16(a, b, acc, 0, 0, 0);
    }
    int n = ntile*16 + m;
    #pragma unroll
    for (int reg = 0; reg < 4; reg++){
      int r = mtile*16 + quad*4 + reg;
      float val = acc[reg];
      if (n < 120){
        xinB[r*136 + n] = f2b(val);
      } else if (r >= 3 && r < 67){
        zs[(size_t)(row0 - 3 + r)*120 + (n - 120)] = f2b(siluf_(val));
      }
    }
  }
  __syncthreads();
  // phase 3: conv1d(4 taps)+silu -> xcg global bf16 + xcB bf16 (K-pad 120..127 = 0)
  #pragma unroll
  for (int j = 0; j < 30; j++){
    int i = tid + j*256;
    int r = i/120, c = i%120;
    float a = cbL[c];
    #pragma unroll
    for (int k = 0; k < 4; k++)
      a += cwL[c*4+k] * b2f(xinB[(r+k)*136 + c]);
    a = siluf_(a);
    short ab = f2b(a);
    xcg[(size_t)(row0 + r)*120 + c] = ab;
    xcB[r*136 + c] = ab;
  }
  for (int i = tid; i < 64*8; i += 256)
    xcB[(i >> 3)*136 + 120 + (i & 7)] = 0;
  __syncthreads();
  // phase 4: x_proj MFMA: wave w -> mtile w; 3 ntiles; K=128
  {
    f32x4 acc0 = {0.f,0.f,0.f,0.f}, acc1 = {0.f,0.f,0.f,0.f}, acc2 = {0.f,0.f,0.f,0.f};
    #pragma unroll
    for (int ks = 0; ks < 4; ks++){
      bhalf8 a  = *(const bhalf8*)&xcB[(wave*16 + m)*136 + ks*32 + quad*8];
      bhalf8 b0 = *(const bhalf8*)&xpB[(0*16 + m)*128 + ks*32 + quad*8];
      bhalf8 b1 = *(const bhalf8*)&xpB[(1*16 + m)*128 + ks*32 + quad*8];
      bhalf8 b2 = *(const bhalf8*)&xpB[(2*16 + m)*128 + ks*32 + quad*8];
      acc0 = __builtin_amdgcn_mfma_f32_16x16x32_bf16(a, b0, acc0, 0, 0, 0);
      acc1 = __builtin_amdgcn_mfma_f32_16x16x32_bf16(a, b1, acc1, 0, 0, 0);
      acc2 = __builtin_amdgcn_mfma_f32_16x16x32_bf16(a, b2, acc2, 0, 0, 0);
    }
    f32x4 accs[3] = {acc0, acc1, acc2};
    #pragma unroll
    for (int nt = 0; nt < 3; nt++){
      int n = nt*16 + m;
      #pragma unroll
      for (int reg = 0; reg < 4; reg++){
        int r = wave*16 + quad*4 + reg;
        float val = accs[nt][reg];
        if (n < 4)       dtsh[r*4 + n] = val;
        else if (n < 36) BC[(size_t)(row0 + r)*32 + (n - 4)] = val;
        if (n >= 4 && n < 20) BL[r*16 + (n - 4)] = val;
      }
    }
  }
  __syncthreads();
  // phase 5: dt_proj + softplus -> delta global (bf16)
  #pragma unroll
  for (int j = 0; j < 30; j++){
    int i = tid + j*256;
    int row = i/120, d = i%120;
    float t0 = dtsh[row*4], t1 = dtsh[row*4+1], t2 = dtsh[row*4+2], t3 = dtsh[row*4+3];
    float a = bdL[d] + t0*Wd5[d*5] + t1*Wd5[d*5+1] + t2*Wd5[d*5+2] + t3*Wd5[d*5+3];
    delta[(size_t)(row0 + row)*120 + d] = f2b(softplusf_(a));
  }
  // phase 6: fused scan pass 1 over this block's two 32-row chunks (no barrier needed:
  // reads dtsh/xcB/BL which are stable after the phase-4 barrier)
  if (tid < 240){
    const int cc = tid / 120, d = tid % 120;
    const int b = row0 / LSEQ;
    const int cglob = ((row0 % LSEQ) >> 5) + cc;
    float A2[16], h[16];
    #pragma unroll
    for (int n = 0; n < 16; n++){ A2[n] = -__expf(A_log[d*16+n]) * 1.44269504f; h[n] = 0.f; }
    bool fastp = true;
    #pragma unroll
    for (int n = 1; n < 16; n++)
      fastp = fastp && (fabsf(A2[n] - (n+1)*A2[0]) <= 1e-4f*fabsf(A2[n]));
    const float w0 = Wd5[d*5], w1 = Wd5[d*5+1], w2 = Wd5[d*5+2], w3 = Wd5[d*5+3];
    const float bd = bdL[d];
    const int rbase = cc*32;
    int base = (cglob*BATCH + b)*(DI*16) + d*16;
    if (fastp){
      float P = 1.f;
      const float A20 = A2[0];
      for (int t = 0; t < 32; t++){
        int row = rbase + t;
        float4 t4 = *(const float4*)&dtsh[row*4];
        float del = softplusf_(bd + t4.x*w0 + t4.y*w1 + t4.z*w2 + t4.w*w3);
        float xcv = b2f(xcB[row*136 + d]);
        float dx = del * xcv;
        float r = exp2f(del * A20);
        P *= r;
        float dA[16]; powers16(r, dA);
        float4 b0 = *(const float4*)&BL[row*16+0];
        float4 b1 = *(const float4*)&BL[row*16+4];
        float4 b2 = *(const float4*)&BL[row*16+8];
        float4 b3 = *(const float4*)&BL[row*16+12];
        h[0]=dA[0]*h[0]+dx*b0.x;  h[1]=dA[1]*h[1]+dx*b0.y;  h[2]=dA[2]*h[2]+dx*b0.z;  h[3]=dA[3]*h[3]+dx*b0.w;
        h[4]=dA[4]*h[4]+dx*b1.x;  h[5]=dA[5]*h[5]+dx*b1.y;  h[6]=dA[6]*h[6]+dx*b1.z;  h[7]=dA[7]*h[7]+dx*b1.w;
        h[8]=dA[8]*h[8]+dx*b2.x;  h[9]=dA[9]*h[9]+dx*b2.y;  h[10]=dA[10]*h[10]+dx*b2.z; h[11]=dA[11]*h[11]+dx*b2.w;
        h[12]=dA[12]*h[12]+dx*b3.x; h[13]=dA[13]*h[13]+dx*b3.y; h[14]=dA[14]*h[14]+dx*b3.z; h[15]=dA[15]*h[15]+dx*b3.w;
      }
      float apv[16]; powers16(P, apv);
      #pragma unroll
      for (int q = 0; q < 4; q++){
        *(float4*)&ap[base + q*4] = *(float4*)&apv[q*4];
        *(float4*)&he[base + q*4] = *(float4*)&h[q*4];
      }
    } else {
      float apv[16];
      #pragma unroll
      for (int n = 0; n < 16; n++) apv[n] = 1.f;
      for (int t = 0; t < 32; t++){
        int row = rbase + t;
        float4 t4 = *(const float4*)&dtsh[row*4];
        float del = softplusf_(bd + t4.x*w0 + t4.y*w1 + t4.z*w2 + t4.w*w3);
        float xcv = b2f(xcB[row*136 + d]);
        float dx = del * xcv;
        #pragma unroll
        for (int n = 0; n < 16; n++){
          float dA = exp2f(del * A2[n]);
          apv[n] *= dA;
          h[n] = dA*h[n] + dx*BL[row*16+n];
        }
      }
      #pragma unroll
      for (int q = 0; q < 4; q++){
        *(float4*)&ap[base + q*4] = *(float4*)&apv[q*4];
        *(float4*)&he[base + q*4] = *(float4*)&h[q*4];
      }
    }
  }
}

// =============== scan pass 2: hierarchical block-parallel chunk scan ===============
__global__ __launch_bounds__(256) void k_scan2(float* __restrict__ ap, const float* __restrict__ he)
{
  __shared__ float aggA[16*17];
  __shared__ float aggB[16*17];
  const int tid = threadIdx.x;
  const int n = tid & 15, j = tid >> 4;
  const int sbase = blockIdx.x*16 + n;
  const int stride = BATCH*DI*16;
  {
    float A = 1.f, B = 0.f;
    int idx = (j*32)*stride + sbase;
    #pragma unroll 4
    for (int k = 0; k < 32; k++){
      float a = ap[idx], h = he[idx];
      B = a*B + h;
      A *= a;
      idx += stride;
    }
    aggA[n*17 + j] = A;
    aggB[n*17 + j] = B;
  }
  __syncthreads();
  if (tid < 16){
    float B = 0.f;
    #pragma unroll
    for (int jj = 0; jj < 16; jj++){
      float Af = aggA[tid*17 + jj];
      float Bf = aggB[tid*17 + jj];
      aggB[tid*17 + jj] = B;
      B = Af*B + Bf;
    }
  }
  __syncthreads();
  {
    float H = aggB[n*17 + j];
    int idx = (j*32)*stride + sbase;
    #pragma unroll 4
    for (int k = 0; k < 32; k++){
      float a = ap[idx], h = he[idx];
      ap[idx] = H;
      H = a*H + h;
      idx += stride;
    }
  }
}

// =============== scan pass 3 + out_proj fused (bf16 inputs) ===============
__global__ __launch_bounds__(128) void k_scan3o(
    const short* __restrict__ delta, const short* __restrict__ xc,
    const float* __restrict__ BC, const short* __restrict__ zs,
    const float* __restrict__ h0, const float* __restrict__ A_log,
    const float* __restrict__ Dsk, const float* __restrict__ opw,
    float* __restrict__ hout)
{
  __shared__ float BCl[TCH*32];
  __shared__ float yL[TCH*124];
  const int tid = threadIdx.x;
  const int c = blockIdx.x % NCH, b = blockIdx.x / NCH;
  const size_t rowbase = (size_t)b*LSEQ + (size_t)c*TCH;
  for (int i = tid; i < TCH*32; i += 128)
    BCl[i] = BC[rowbase*32 + i];
  __syncthreads();
  const int d = tid;
  if (d < DI){
    float A2[16], h[16];
    int base = (c*BATCH + b)*(DI*16) + d*16;
    #pragma unroll
    for (int n = 0; n < 16; n++){
      A2[n] = -__expf(A_log[d*16+n]) * 1.44269504f;
      h[n] = h0[base+n];
    }
    bool fastp = true;
    #pragma unroll
    for (int n = 1; n < 16; n++)
      fastp = fastp && (fabsf(A2[n] - (n+1)*A2[0]) <= 1e-4f*fabsf(A2[n]));
    float Dv = Dsk[d];
    if (fastp){
      const float A20 = A2[0];
      for (int t = 0; t < TCH; t++){
        float del = b2f(delta[(rowbase+t)*DI + d]);
        float xcv = b2f(xc[(rowbase+t)*DI + d]);
        float zv  = b2f(zs[(rowbase+t)*DI + d]);
        float dx = del * xcv;
        float r = exp2f(del * A20);
        float dA[16]; powers16(r, dA);
        float4 b0 = *(const float4*)&BCl[t*32+0];
        float4 b1 = *(const float4*)&BCl[t*32+4];
        float4 b2 = *(const float4*)&BCl[t*32+8];
        float4 b3 = *(const float4*)&BCl[t*32+12];
        float4 c0 = *(const float4*)&BCl[t*32+16];
        float4 c1 = *(const float4*)&BCl[t*32+20];
        float4 c2 = *(const float4*)&BCl[t*32+24];
        float4 c3 = *(const float4*)&BCl[t*32+28];
        h[0]=dA[0]*h[0]+dx*b0.x;  h[1]=dA[1]*h[1]+dx*b0.y;  h[2]=dA[2]*h[2]+dx*b0.z;  h[3]=dA[3]*h[3]+dx*b0.w;
        h[4]=dA[4]*h[4]+dx*b1.x;  h[5]=dA[5]*h[5]+dx*b1.y;  h[6]=dA[6]*h[6]+dx*b1.z;  h[7]=dA[7]*h[7]+dx*b1.w;
        h[8]=dA[8]*h[8]+dx*b2.x;  h[9]=dA[9]*h[9]+dx*b2.y;  h[10]=dA[10]*h[10]+dx*b2.z; h[11]=dA[11]*h[11]+dx*b2.w;
        h[12]=dA[12]*h[12]+dx*b3.x; h[13]=dA[13]*h[13]+dx*b3.y; h[14]=dA[14]*h[14]+dx*b3.z; h[15]=dA[15]*h[15]+dx*b3.w;
        float acc = h[0]*c0.x + h[1]*c0.y + h[2]*c0.z + h[3]*c0.w
                  + h[4]*c1.x + h[5]*c1.y + h[6]*c1.z + h[7]*c1.w
                  + h[8]*c2.x + h[9]*c2.y + h[10]*c2.z + h[11]*c2.w
                  + h[12]*c3.x + h[13]*c3.y + h[14]*c3.z + h[15]*c3.w;
        yL[t*124 + d] = (acc + Dv*xcv) * zv;
      }
    } else {
      for (int t = 0; t < TCH; t++){
        float del = b2f(delta[(rowbase+t)*DI + d]);
        float xcv = b2f(xc[(rowbase+t)*DI + d]);
        float zv  = b2f(zs[(rowbase+t)*DI + d]);
        float dx = del * xcv;
        float acc = 0.f;
        #pragma unroll
        for (int n = 0; n < 16; n++){
          float dA = exp2f(del * A2[n]);
          h[n] = dA*h[n] + dx*BCl[t*32+n];
          acc += h[n]*BCl[t*32+16+n];
        }
        yL[t*124 + d] = (acc + Dv*xcv) * zv;
      }
    }
  }
  __syncthreads();
  if (tid < 120){
    const int cg = tid % 15, rg = tid / 15;
    float acc[4][4];
    #pragma unroll
    for (int r = 0; r < 4; r++){ acc[r][0]=0.f; acc[r][1]=0.f; acc[r][2]=0.f; acc[r][3]=0.f; }
    for (int kg = 0; kg < 30; kg++){
      int k = kg*4;
      float4 b0 = *(const float4*)&opw[(size_t)(cg*4+0)*120 + k];
      float4 b1 = *(const float4*)&opw[(size_t)(cg*4+1)*120 + k];
      float4 b2 = *(const float4*)&opw[(size_t)(cg*4+2)*120 + k];
      float4 b3 = *(const float4*)&opw[(size_t)(cg*4+3)*120 + k];
      #pragma unroll
      for (int r = 0; r < 4; r++){
        float4 a = *(const float4*)&yL[(rg*4+r)*124 + k];
        acc[r][0] += a.x*b0.x + a.y*b0.y + a.z*b0.z + a.w*b0.w;
        acc[r][1] += a.x*b1.x + a.y*b1.y + a.z*b1.z + a.w*b1.w;
        acc[r][2] += a.x*b2.x + a.y*b2.y + a.z*b2.z + a.w*b2.w;
        acc[r][3] += a.x*b3.x + a.y*b3.y + a.z*b3.z + a.w*b3.w;
      }
    }
    #pragma unroll
    for (int r = 0; r < 4; r++){
      float4 v; v.x=acc[r][0]; v.y=acc[r][1]; v.z=acc[r][2]; v.w=acc[r][3];
      *(float4*)&hout[(rowbase + rg*4 + r)*60 + cg*4] = v;
    }
  }
}

// =============== conv2d weight pack: w[co][ci][3][3] -> bf16 wB[tap][co64][ci64] ===============
__global__ __launch_bounds__(256) void k_wB(const float* __restrict__ w, short* __restrict__ wB)
{
  int i = blockIdx.x*256 + threadIdx.x;
  if (i >= 9*64*64) return;
  int ci = i & 63, co = (i >> 6) & 63, tap = i >> 12;
  float v = 0.f;
  if (co < 60 && ci < 60) v = w[((size_t)co*60 + ci)*9 + tap];
  wB[i] = f2b(v);
}

// =============== 3x3 SAME conv2d via bf16 MFMA + bias + residual ===============
__global__ __launch_bounds__(256) void k_conv2d(
    const float* __restrict__ hin, const short* __restrict__ wB,
    const float* __restrict__ cb, const float* __restrict__ xres,
    float* __restrict__ out)
{
  __shared__ short tile[3*66*72];
  const int tid = threadIdx.x;
  const int blk = blockIdx.x;
  const int xhalf = blk & 1;
  const int yy = (blk >> 1) & 127;
  const int b = blk >> 8;
  const int x0 = xhalf*64;
  for (int i = tid; i < 3*66*72; i += 256){
    int ci = i % 72;
    int xx = (i / 72) % 66;
    int row = i / (72*66);
    int gy = yy - 1 + row, gx = x0 - 1 + xx;
    float v = 0.f;
    if (ci < 60 && gy >= 0 && gy < HH && gx >= 0 && gx < WW)
      v = hin[((size_t)b*LSEQ + gy*WW + gx)*60 + ci];
    tile[i] = f2b(v);
  }
  __syncthreads();
  const int wave = tid >> 6, lane = tid & 63;
  const int m = lane & 15, quad = lane >> 4;
  f32x4 acc0 = {0.f,0.f,0.f,0.f}, acc1 = {0.f,0.f,0.f,0.f};
  f32x4 acc2 = {0.f,0.f,0.f,0.f}, acc3 = {0.f,0.f,0.f,0.f};
  #pragma unroll
  for (int tap = 0; tap < 9; tap++){
    const int ky = tap/3, kx = tap%3;
    const short* arow = &tile[(ky*66 + wave*16 + m + kx)*72];
    const short* brow = wB + tap*4096;
    #pragma unroll
    for (int kh = 0; kh < 2; kh++){
      const int k0 = kh*32 + quad*8;
      bhalf8 a = *(const bhalf8*)(arow + k0);
      bhalf8 b0 = *(const bhalf8*)(brow + (0*16 + m)*64 + k0);
      bhalf8 b1 = *(const bhalf8*)(brow + (1*16 + m)*64 + k0);
      bhalf8 b2 = *(const bhalf8*)(brow + (2*16 + m)*64 + k0);
      bhalf8 b3 = *(const bhalf8*)(brow + (3*16 + m)*64 + k0);
      acc0 = __builtin_amdgcn_mfma_f32_16x16x32_bf16(a, b0, acc0, 0, 0, 0);
      acc1 = __builtin_amdgcn_mfma_f32_16x16x32_bf16(a, b1, acc1, 0, 0, 0);
      acc2 = __builtin_amdgcn_mfma_f32_16x16x32_bf16(a, b2, acc2, 0, 0, 0);
      acc3 = __builtin_amdgcn_mfma_f32_16x16x32_bf16(a, b3, acc3, 0, 0, 0);
    }
  }
  const size_t rowb = (size_t)b*LSEQ + yy*WW + x0;
  f32x4 accs[4] = {acc0, acc1, acc2, acc3};
  #pragma unroll
  for (int nt = 0; nt < 4; nt++){
    int co = nt*16 + m;
    if (co < 60){
      float bias = cb[co];
      #pragma unroll
      for (int reg = 0; reg < 4; reg++){
        int px = wave*16 + quad*4 + reg;
        size_t o = (rowb + px)*60 + co;
        out[o] = accs[nt][reg] + bias + xres[o];
      }
    }
  }
}

extern "C" void kernel_launch(void* const* d_in, const int* in_sizes, int n_in,
                              void* d_out, int out_size, void* d_ws, size_t ws_size,
                              hipStream_t stream)
{
  const float* x      = (const float*)d_in[0];
  const float* ln_w   = (const float*)d_in[1];
  const float* ln_b   = (const float*)d_in[2];
  const float* ipw    = (const float*)d_in[3];
  const float* cw     = (const float*)d_in[4];
  const float* cb1    = (const float*)d_in[5];
  const float* xpw    = (const float*)d_in[6];
  const float* dtw    = (const float*)d_in[7];
  const float* dtb    = (const float*)d_in[8];
  const float* A_log  = (const float*)d_in[9];
  const float* Dsk    = (const float*)d_in[10];
  const float* opw    = (const float*)d_in[11];
  const float* c2w    = (const float*)d_in[12];
  const float* c2b    = (const float*)d_in[13];
  float* out = (float*)d_out;

  char* ws = (char*)d_ws;
  size_t off = 0;
  short* zsb   = (short*)(ws + off); off += (size_t)BATCH*LSEQ*DI*2;
  short* xcb   = (short*)(ws + off); off += (size_t)BATCH*LSEQ*DI*2;
  short* dlt   = (short*)(ws + off); off += (size_t)BATCH*LSEQ*DI*2;
  float* BC    = (float*)(ws + off); off += (size_t)BATCH*LSEQ*32*4;
  float* apb   = (float*)(ws + off); off += (size_t)NCH*BATCH*DI*16*4;
  float* heb   = (float*)(ws + off); off += (size_t)NCH*BATCH*DI*16*4;
  float* hcur  = (float*)(ws + off); off += (size_t)BATCH*LSEQ*DM*4;
  short* wBb   = (short*)(ws + off); off += (size_t)9*64*64*2;
  short* pkb   = (short*)(ws + off); off += (size_t)(2*240*64 + 2*48*128)*2;

  const int rows = BATCH*LSEQ;
  k_pack<<<(2*240*64 + 2*48*128 + 255)/256, 256, 0, stream>>>(ipw, xpw, pkb);
  for (int layer = 0; layer < 2; layer++){
    const float* src = (layer == 0) ? x : hcur;
    k_lnxp<<<rows/64, 256, 0, stream>>>(src, ln_w + layer*DM, ln_b + layer*DM,
                                        pkb + (size_t)layer*240*64,
                                        cw + layer*DI*4, cb1 + layer*DI,
                                        pkb + 30720 + (size_t)layer*48*128,
                                        dtw + (size_t)layer*DI*4, dtb + layer*DI,
                                        A_log + (size_t)layer*DI*16,
                                        zsb, xcb, dlt, BC, apb, heb);
    k_scan2<<<BATCH*DI, 256, 0, stream>>>(apb, heb);
    k_scan3o<<<BATCH*NCH, 128, 0, stream>>>(dlt, xcb, BC, zsb, apb, A_log + (size_t)layer*DI*16,
                                            Dsk + layer*DI, opw + (size_t)layer*DM*DI, hcur);
  }
  k_wB<<<(9*64*64+255)/256, 256, 0, stream>>>(c2w, wBb);
  k_conv2d<<<BATCH*HH*2, 256, 0, stream>>>(hcur, wBb, c2b, x, out);
}